// Round 2
// baseline (942.601 us; speedup 1.0000x reference)
//
#include <hip/hip_runtime.h>
#include <math.h>

// HGPSLPool: B=64 graphs, N=1024 nodes, D=128, EPG=8192, K=820.
// Outputs (concat, float32 view): feat_p [B*K*D], weights [B*K*K], perm [B*K], x_score [NTOT].

static constexpr int B_    = 64;
static constexpr int N_    = 1024;
static constexpr int D_    = 128;
static constexpr int NTOT_ = B_ * N_;     // 65536
static constexpr int ETOT_ = B_ * 8192;   // 524288
static constexpr int K_    = 820;
static constexpr int BK_   = B_ * K_;     // 52480
static constexpr float NEG_ = 0.2f;

__device__ __forceinline__ float lrelu(float x) { return x >= 0.f ? x : NEG_ * x; }

// ---- wa = W @ a (fp64), 1 block x 128 ----
__global__ void k_wa(const float* __restrict__ W, const float* __restrict__ a,
                     double* __restrict__ wa64) {
  int d = threadIdx.x;
  double s = 0.0;
  for (int k = 0; k < D_; ++k) s += (double)W[d * D_ + k] * (double)a[k];
  wa64[d] = s;
}

// ---- degrees (self-loops included, matching ref) ----
__global__ void k_deg(const int* __restrict__ src, const int* __restrict__ dst,
                      int* __restrict__ outd, int* __restrict__ ind) {
  int e = blockIdx.x * 256 + threadIdx.x;
  atomicAdd(&outd[src[e]], 1);
  atomicAdd(&ind[dst[e]], 1);
}

// ---- exclusive scan, single block of 1024, thread-serial chunks ----
__global__ void k_exscan(const int* __restrict__ in, int* __restrict__ out, int n) {
  __shared__ int bs[1024];
  int t = threadIdx.x;
  int per = (n + 1023) >> 10;
  int s0 = t * per, s1 = min(s0 + per, n);
  int s = 0;
  for (int i = s0; i < s1; ++i) s += in[i];
  bs[t] = s;
  __syncthreads();
  for (int off = 1; off < 1024; off <<= 1) {
    int v = (t >= off) ? bs[t - off] : 0;
    __syncthreads();
    bs[t] += v;
    __syncthreads();
  }
  int base = (t == 0) ? 0 : bs[t - 1];
  for (int i = s0; i < s1; ++i) { out[i] = base; base += in[i]; }
  if (t == 1023) out[n] = base;
}

// ---- fill dst-CSR ----
__global__ void k_fillcsr(const int* __restrict__ dst, const int* __restrict__ rowptr,
                          int* __restrict__ cursor, int* __restrict__ col) {
  int e = blockIdx.x * 256 + threadIdx.x;
  int v = dst[e];
  int p = atomicAdd(&cursor[v], 1);
  col[rowptr[v] + p] = e;
}

// ---- neighbor aggregation + info + attn + x_score (fp64 for top-k ordering) ----
// one wave per node; lane holds dims 2l, 2l+1
__global__ void k_agg(const float* __restrict__ feat, const float* __restrict__ e_feat,
                      const int* __restrict__ src, const int* __restrict__ col,
                      const int* __restrict__ rowptr, const int* __restrict__ ind,
                      const int* __restrict__ outd, const double* __restrict__ wa64,
                      float* __restrict__ out_xs, double* __restrict__ xs64) {
  int gid = blockIdx.x * 256 + threadIdx.x;
  int v = gid >> 6, lane = gid & 63;
  const float2* f2 = (const float2*)feat;
  float2 f = f2[(size_t)v * 64 + lane];
  double ax = 0.0, ay = 0.0;
  int r0 = rowptr[v], r1 = rowptr[v + 1];
  for (int sP = r0; sP < r1; ++sP) {
    int e = col[sP];
    int u = src[e];
    if (u == v) continue;                       // remove_self_loop for messages
    double sc = (double)e_feat[e] / sqrt(fmax((double)outd[u], 1.0));
    float2 fu = f2[(size_t)u * 64 + lane];
    ax += (double)fu.x * sc;
    ay += (double)fu.y * sc;
  }
  double dn = 1.0 / sqrt(fmax((double)ind[v], 1.0));
  double info = fabs((double)f.x - ax * dn) + fabs((double)f.y - ay * dn);
  double dot = (double)f.x * wa64[2 * lane] + (double)f.y * wa64[2 * lane + 1];
#pragma unroll
  for (int off = 32; off > 0; off >>= 1) {
    info += __shfl_down(info, off);
    dot  += __shfl_down(dot, off);
  }
  if (lane == 0) {
    double sA = dot >= 0.0 ? dot : 0.2 * dot;   // leaky_relu 0.2
    double attn = 1.0 / (1.0 + exp(-sA));
    double x = info * attn;
    out_xs[v] = (float)x;
    xs64[v] = x;
  }
}

// ---- per-graph top-K via bitonic sort of (val desc, idx asc) pairs ----
__global__ void k_topk(const double* __restrict__ xs64, float* __restrict__ out_perm,
                       int* __restrict__ perm_i, int* __restrict__ maskarr) {
  __shared__ double dv[1024];
  __shared__ int di[1024];
  int b = blockIdx.x, t = threadIdx.x;
  for (int i = t; i < 1024; i += 256) { dv[i] = xs64[b * 1024 + i]; di[i] = i; }
  __syncthreads();
  for (int k2 = 2; k2 <= 1024; k2 <<= 1) {
    for (int j = k2 >> 1; j > 0; j >>= 1) {
      for (int i = t; i < 1024; i += 256) {
        int ixj = i ^ j;
        if (ixj > i) {
          double a = dv[i], c = dv[ixj];
          int ia = di[i], ic = di[ixj];
          bool pre = (a > c) || (a == c && ia < ic);   // a precedes c in desc order
          bool dir = ((i & k2) == 0);                  // true -> descending segment
          if (pre != dir) { dv[i] = c; dv[ixj] = a; di[i] = ic; di[ixj] = ia; }
        }
      }
      __syncthreads();
    }
  }
  for (int r = t; r < K_; r += 256) {
    int node = b * N_ + di[r];
    int pos = b * K_ + r;
    out_perm[pos] = (float)node;    // output buffer is float32 view
    perm_i[pos] = node;
    maskarr[node] = pos;
  }
}

// ---- gather feat_p + wsrc/wdst dots (one wave per pooled row) ----
__global__ void k_gather(const float* __restrict__ feat, const int* __restrict__ perm_i,
                         const float* __restrict__ att, float* __restrict__ out_featp,
                         float* __restrict__ wsrc, float* __restrict__ wdst) {
  int gid = blockIdx.x * 256 + threadIdx.x;
  int p = gid >> 6, lane = gid & 63;
  int node = perm_i[p];
  float2 f = ((const float2*)feat)[(size_t)node * 64 + lane];
  ((float2*)out_featp)[(size_t)p * 64 + lane] = f;
  double s1 = (double)f.x * (double)att[2 * lane] + (double)f.y * (double)att[2 * lane + 1];
  double s2 = (double)f.x * (double)att[D_ + 2 * lane] + (double)f.y * (double)att[D_ + 2 * lane + 1];
#pragma unroll
  for (int off = 32; off > 0; off >>= 1) {
    s1 += __shfl_down(s1, off);
    s2 += __shfl_down(s2, off);
  }
  if (lane == 0) { wsrc[p] = (float)s1; wdst[p] = (float)s2; }
}

// ---- pooled-subgraph edge CSR keyed by pooled dst column ----
__global__ void k_cnt2(const int* __restrict__ src, const int* __restrict__ dst,
                       const int* __restrict__ maskarr, int* __restrict__ cnt2) {
  int e = blockIdx.x * 256 + threadIdx.x;
  int nr = maskarr[src[e]], nc = maskarr[dst[e]];
  if (nr >= 0 && nc >= 0) atomicAdd(&cnt2[nc], 1);
}

__global__ void k_fill2(const int* __restrict__ src, const int* __restrict__ dst,
                        const int* __restrict__ maskarr, const float* __restrict__ e_feat,
                        const int* __restrict__ rowptr2, int* __restrict__ cursor2,
                        int* __restrict__ colii, float* __restrict__ colval) {
  int e = blockIdx.x * 256 + threadIdx.x;
  int nr = maskarr[src[e]], nc = maskarr[dst[e]];
  if (nr >= 0 && nc >= 0) {
    int p = atomicAdd(&cursor2[nc], 1);
    int s = rowptr2[nc] + p;
    colii[s] = nr;                 // global pooled src index (b*K + i)
    colval[s] = 1.0f * e_feat[e];  // LAMB = 1
  }
}

// ---- dedupe duplicate (i,j) edges per column (must sum E before nonlinear clip) ----
__global__ void k_dedupe(const int* __restrict__ rowptr2, int* __restrict__ colii,
                         float* __restrict__ colval, int* __restrict__ ucnt) {
  int c = blockIdx.x * 256 + threadIdx.x;
  int r0 = rowptr2[c], r1 = rowptr2[c + 1];
  int w = r0;
  for (int s = r0; s < r1; ++s) {
    int ii = colii[s];
    if (ii < 0) continue;
    float E = colval[s];
    for (int t2 = s + 1; t2 < r1; ++t2)
      if (colii[t2] == ii) { E += colval[t2]; colii[t2] = -1; }
    colii[w] = ii; colval[w] = E; ++w;
  }
  ucnt[c] = w - r0;
}

// ---- per-graph sort of wsrc (desc) + prefix sums ----
__global__ void k_gsort(const float* __restrict__ wsrc, float* __restrict__ ws_sorted,
                        float* __restrict__ psum) {
  __shared__ float sv[1024];
  __shared__ float sc[1024];
  int b = blockIdx.x, t = threadIdx.x;
  for (int i = t; i < 1024; i += 256) sv[i] = (i < K_) ? wsrc[b * K_ + i] : -INFINITY;
  __syncthreads();
  for (int k2 = 2; k2 <= 1024; k2 <<= 1) {
    for (int j = k2 >> 1; j > 0; j >>= 1) {
      for (int i = t; i < 1024; i += 256) {
        int ixj = i ^ j;
        if (ixj > i) {
          float a = sv[i], c = sv[ixj];
          bool dir = ((i & k2) == 0);
          bool swapv = dir ? (c > a) : (a > c);
          if (swapv) { sv[i] = c; sv[ixj] = a; }
        }
      }
      __syncthreads();
    }
  }
  for (int i = t; i < 1024; i += 256) { ws_sorted[b * 1024 + i] = sv[i]; sc[i] = sv[i]; }
  __syncthreads();
  for (int off = 1; off < 1024; off <<= 1) {
    float tmp[4];
    for (int i = t, q = 0; i < 1024; i += 256, ++q) tmp[q] = (i >= off) ? sc[i - off] : 0.f;
    __syncthreads();
    for (int i = t, q = 0; i < 1024; i += 256, ++q) sc[i] += tmp[q];
    __syncthreads();
  }
  if (t == 0) psum[b * 1025] = 0.f;
  for (int i = t; i < 1024; i += 256) psum[b * 1025 + 1 + i] = sc[i];
}

// count of entries > thr in desc-sorted array of length K_
__device__ __forceinline__ int cnt_gt(const float* __restrict__ arr, float thr) {
  int lo = 0, hi = K_;
  while (lo < hi) {
    int mid = (lo + hi) >> 1;
    if (arr[mid] > thr) lo = mid + 1; else hi = mid;
  }
  return lo;
}

// ---- tau per column via bisection on g(t) = sum max(z-t,0) = 1 ----
// column z_i = lrelu(wsrc_i + wd_j) [+ sparse E]; base part evaluated O(log K)
// from per-graph sorted wsrc + prefix sums (lrelu split handled at p = #{ws > -wd}).
// CORRECTNESS HARDENING vs round 1 (inf in weights):
//  (a) sparse membership correction uses the IDENTICAL predicate (wsrc > wthr)
//      that cnt_gt counted with -> cc >= 1 provably (max-z entry always re-added).
//  (b) tau* is mathematically in [mz-1, mz); clamp the result -> never inf/nan.
__global__ void k_tau(const float* __restrict__ wsrc, const float* __restrict__ wdst,
                      const float* __restrict__ ws_sorted, const float* __restrict__ psum,
                      const int* __restrict__ rowptr2, const int* __restrict__ ucnt,
                      const int* __restrict__ colii, const float* __restrict__ colval,
                      float* __restrict__ tauv) {
  int c = blockIdx.x * 256 + threadIdx.x;
  int b = c / K_;
  float wd = wdst[c];
  const float* wss = ws_sorted + b * 1024;
  const float* PS = psum + b * 1025;
  int p = cnt_gt(wss, -wd);
  int r0 = rowptr2[c], m = ucnt[c];
  float mz = lrelu(wss[0] + wd);
  for (int s = 0; s < m; ++s) {
    float bse = lrelu(wsrc[colii[r0 + s]] + wd);
    mz = fmaxf(mz, bse + colval[r0 + s]);      // E > 0 for this input (e_feat=1, LAMB=1)
  }
  float lo = mz - 1.0f, hi = mz;               // g(mz)=0<1, g(mz-1)>=1
  for (int it = 0; it < 32; ++it) {
    float t = 0.5f * (lo + hi);
    float wthr = (t >= 0.f ? t : 5.f * t) - wd;
    int n = cnt_gt(wss, wthr);
    float bsum = (n <= p) ? (PS[n] + n * wd)
                          : (PS[p] + p * wd + NEG_ * (PS[n] - PS[p] + (n - p) * wd));
    float g = bsum - n * t;
    for (int s = 0; s < m; ++s) {
      float bse = lrelu(wsrc[colii[r0 + s]] + wd);
      float E = colval[r0 + s];
      g += fmaxf(bse + E - t, 0.f) - fmaxf(bse - t, 0.f);
    }
    if (g > 1.f) lo = t; else hi = t;
  }
  float t = lo;                                 // t <= tau*, within ~2^-32 of it
  float wthr = (t >= 0.f ? t : 5.f * t) - wd;
  int n = cnt_gt(wss, wthr);
  float S = (n <= p) ? (PS[n] + n * wd)
                     : (PS[p] + p * wd + NEG_ * (PS[n] - PS[p] + (n - p) * wd));
  int cc = n;
  for (int s = 0; s < m; ++s) {
    float ws_i = wsrc[colii[r0 + s]];
    float bse = lrelu(ws_i + wd);
    float zz = bse + colval[r0 + s];
    if (ws_i > wthr) { S -= bse; cc -= 1; }    // same predicate as cnt_gt -> exact cancel
    if (zz > t)      { S += zz;  cc += 1; }
  }
  float tau;
  if (cc < 1) {
    tau = mz - 1.0f;                            // degenerate fallback (single support)
  } else {
    tau = (S - 1.0f) / (float)cc;
  }
  // true tau* always lies in [mz-1, mz); clamp kills any residual inf/nan
  tau = fminf(fmaxf(tau, mz - 1.0f), mz);
  tauv[c] = tau;
}

// ---- dense weights: coalesced j-fastest, ignores sparse E (fixed up next) ----
__global__ void k_dense(const float* __restrict__ wsrc, const float* __restrict__ wdst,
                        const float* __restrict__ tauv, float* __restrict__ out_w) {
  int j = blockIdx.x * 256 + threadIdx.x;
  if (j >= K_) return;
  int row = blockIdx.y;                         // b*K + i
  int b = row / K_;
  int c = b * K_ + j;
  float z = lrelu(wsrc[row] + wdst[c]);
  float v = z - tauv[c];
  out_w[(size_t)row * K_ + j] = (v > 1e-9f) ? v : 0.f;
}

// ---- rewrite the edge-perturbed entries with the correct value ----
__global__ void k_fix(const float* __restrict__ wsrc, const float* __restrict__ wdst,
                      const float* __restrict__ tauv, const int* __restrict__ rowptr2,
                      const int* __restrict__ ucnt, const int* __restrict__ colii,
                      const float* __restrict__ colval, float* __restrict__ out_w) {
  int c = blockIdx.x * 256 + threadIdx.x;
  int b = c / K_;
  int j = c - b * K_;
  float wd = wdst[c], ta = tauv[c];
  int r0 = rowptr2[c], m = ucnt[c];
  for (int s = 0; s < m; ++s) {
    int nr = colii[r0 + s];
    float z = lrelu(wsrc[nr] + wd) + colval[r0 + s];
    float v = z - ta;
    out_w[(size_t)nr * K_ + j] = (v > 1e-9f) ? v : 0.f;
  }
}

extern "C" void kernel_launch(void* const* d_in, const int* in_sizes, int n_in,
                              void* d_out, int out_size, void* d_ws, size_t ws_size,
                              hipStream_t stream) {
  const float* feat   = (const float*)d_in[0];
  const float* e_feat = (const float*)d_in[1];
  const float* W      = (const float*)d_in[2];
  const float* a      = (const float*)d_in[3];
  const float* att    = (const float*)d_in[4];
  const int*   src    = (const int*)d_in[5];
  const int*   dst    = (const int*)d_in[6];

  float* out_featp = (float*)d_out;                       // [BK*D]
  float* out_w     = out_featp + (size_t)BK_ * D_;        // [BK*K]
  float* out_perm  = out_w + (size_t)BK_ * K_;            // [BK]
  float* out_xs    = out_perm + BK_;                      // [NTOT]

  char* wsp = (char*)d_ws;
  auto carve = [&](size_t bytes) -> void* {
    void* pp = (void*)wsp;
    wsp += (bytes + 255) & ~(size_t)255;
    return pp;
  };
  double* xs64     = (double*)carve((size_t)NTOT_ * 8);
  double* wa64     = (double*)carve((size_t)D_ * 8);
  float* wsrc      = (float*)carve((size_t)BK_ * 4);
  float* wdst      = (float*)carve((size_t)BK_ * 4);
  float* tauv      = (float*)carve((size_t)BK_ * 4);
  float* colval    = (float*)carve((size_t)ETOT_ * 4);
  float* ws_sorted = (float*)carve((size_t)B_ * 1024 * 4);
  float* psum      = (float*)carve((size_t)B_ * 1025 * 4);
  int* rowptr      = (int*)carve((size_t)(NTOT_ + 1) * 4);
  int* rowptr2     = (int*)carve((size_t)(BK_ + 1) * 4);
  int* col         = (int*)carve((size_t)ETOT_ * 4);
  int* colii       = (int*)carve((size_t)ETOT_ * 4);
  int* perm_i      = (int*)carve((size_t)BK_ * 4);
  size_t zbytes    = ((size_t)NTOT_ * 3 + (size_t)BK_ * 2) * 4;
  int* zblk        = (int*)carve(zbytes);
  int* in_deg      = zblk;
  int* out_deg     = zblk + NTOT_;
  int* cursor      = zblk + 2 * NTOT_;
  int* cnt2        = zblk + 3 * NTOT_;
  int* cursor2     = cnt2 + BK_;
  int* maskarr     = (int*)carve((size_t)NTOT_ * 4);

  hipMemsetAsync(zblk, 0, zbytes, stream);
  hipMemsetAsync(maskarr, 0xFF, (size_t)NTOT_ * 4, stream);   // -1

  k_wa<<<1, 128, 0, stream>>>(W, a, wa64);
  k_deg<<<ETOT_ / 256, 256, 0, stream>>>(src, dst, out_deg, in_deg);
  k_exscan<<<1, 1024, 0, stream>>>(in_deg, rowptr, NTOT_);
  k_fillcsr<<<ETOT_ / 256, 256, 0, stream>>>(dst, rowptr, cursor, col);
  k_agg<<<NTOT_ / 4, 256, 0, stream>>>(feat, e_feat, src, col, rowptr, in_deg, out_deg,
                                       wa64, out_xs, xs64);
  k_topk<<<B_, 256, 0, stream>>>(xs64, out_perm, perm_i, maskarr);
  k_gather<<<BK_ / 4, 256, 0, stream>>>(feat, perm_i, att, out_featp, wsrc, wdst);
  k_cnt2<<<ETOT_ / 256, 256, 0, stream>>>(src, dst, maskarr, cnt2);
  k_exscan<<<1, 1024, 0, stream>>>(cnt2, rowptr2, BK_);
  k_fill2<<<ETOT_ / 256, 256, 0, stream>>>(src, dst, maskarr, e_feat, rowptr2, cursor2,
                                           colii, colval);
  k_dedupe<<<BK_ / 256, 256, 0, stream>>>(rowptr2, colii, colval, cursor2);
  k_gsort<<<B_, 256, 0, stream>>>(wsrc, ws_sorted, psum);
  k_tau<<<BK_ / 256, 256, 0, stream>>>(wsrc, wdst, ws_sorted, psum, rowptr2, cursor2,
                                       colii, colval, tauv);
  k_dense<<<dim3(4, BK_), 256, 0, stream>>>(wsrc, wdst, tauv, out_w);
  k_fix<<<BK_ / 256, 256, 0, stream>>>(wsrc, wdst, tauv, rowptr2, cursor2, colii, colval,
                                       out_w);
}

// Round 3
// 921.301 us; speedup vs baseline: 1.0231x; 1.0231x over previous
//
#include <hip/hip_runtime.h>
#include <math.h>

// HGPSLPool: B=64 graphs, N=1024 nodes, D=128, EPG=8192, K=820.
// Outputs (concat, float32 view): feat_p [B*K*D], weights [B*K*K], perm [B*K], x_score [NTOT].

static constexpr int B_    = 64;
static constexpr int N_    = 1024;
static constexpr int D_    = 128;
static constexpr int NTOT_ = B_ * N_;     // 65536
static constexpr int ETOT_ = B_ * 8192;   // 524288
static constexpr int K_    = 820;
static constexpr int BK_   = B_ * K_;     // 52480
static constexpr float NEG_ = 0.2f;
static constexpr int CPB_  = 16;          // k_tau: chunks per graph
static constexpr int CH_   = 52;          // columns per chunk (16*52=832 >= 820)
static constexpr int MAXM_ = 40;          // preloaded sparse entries per column

__device__ __forceinline__ float lrelu(float x) { return x >= 0.f ? x : NEG_ * x; }

// ---- wa = W @ a (fp64), 1 block x 128 ----
__global__ void k_wa(const float* __restrict__ W, const float* __restrict__ a,
                     double* __restrict__ wa64) {
  int d = threadIdx.x;
  double s = 0.0;
  for (int k = 0; k < D_; ++k) s += (double)W[d * D_ + k] * (double)a[k];
  wa64[d] = s;
}

// ---- degrees (self-loops included, matching ref) ----
__global__ void k_deg(const int* __restrict__ src, const int* __restrict__ dst,
                      int* __restrict__ outd, int* __restrict__ ind) {
  int e = blockIdx.x * 256 + threadIdx.x;
  atomicAdd(&outd[src[e]], 1);
  atomicAdd(&ind[dst[e]], 1);
}

// ---- per-node symmetric-norm scales (lane-invariant work hoisted out of k_agg) ----
__global__ void k_scale(const int* __restrict__ outd, const int* __restrict__ ind,
                        double* __restrict__ sn64, double* __restrict__ dn64) {
  int v = blockIdx.x * 256 + threadIdx.x;
  sn64[v] = 1.0 / sqrt(fmax((double)outd[v], 1.0));
  dn64[v] = 1.0 / sqrt(fmax((double)ind[v], 1.0));
}

// ---- exclusive scan, single block of 1024, thread-serial chunks ----
__global__ void k_exscan(const int* __restrict__ in, int* __restrict__ out, int n) {
  __shared__ int bs[1024];
  int t = threadIdx.x;
  int per = (n + 1023) >> 10;
  int s0 = t * per, s1 = min(s0 + per, n);
  int s = 0;
  for (int i = s0; i < s1; ++i) s += in[i];
  bs[t] = s;
  __syncthreads();
  for (int off = 1; off < 1024; off <<= 1) {
    int v = (t >= off) ? bs[t - off] : 0;
    __syncthreads();
    bs[t] += v;
    __syncthreads();
  }
  int base = (t == 0) ? 0 : bs[t - 1];
  for (int i = s0; i < s1; ++i) { out[i] = base; base += in[i]; }
  if (t == 1023) out[n] = base;
}

// ---- fill dst-CSR ----
__global__ void k_fillcsr(const int* __restrict__ dst, const int* __restrict__ rowptr,
                          int* __restrict__ cursor, int* __restrict__ col) {
  int e = blockIdx.x * 256 + threadIdx.x;
  int v = dst[e];
  int p = atomicAdd(&cursor[v], 1);
  col[rowptr[v] + p] = e;
}

// ---- neighbor aggregation + info + attn + x_score (fp64 for top-k ordering) ----
// one wave per node; lane holds dims 2l, 2l+1
__global__ void k_agg(const float* __restrict__ feat, const float* __restrict__ e_feat,
                      const int* __restrict__ src, const int* __restrict__ col,
                      const int* __restrict__ rowptr, const double* __restrict__ sn64,
                      const double* __restrict__ dn64, const double* __restrict__ wa64,
                      float* __restrict__ out_xs, double* __restrict__ xs64) {
  int gid = blockIdx.x * 256 + threadIdx.x;
  int v = gid >> 6, lane = gid & 63;
  const float2* f2 = (const float2*)feat;
  float2 f = f2[(size_t)v * 64 + lane];
  double ax = 0.0, ay = 0.0;
  int r0 = rowptr[v], r1 = rowptr[v + 1];
  for (int sP = r0; sP < r1; ++sP) {
    int e = col[sP];
    int u = src[e];
    if (u == v) continue;                       // remove_self_loop for messages
    double sc = (double)e_feat[e] * sn64[u];
    float2 fu = f2[(size_t)u * 64 + lane];
    ax += (double)fu.x * sc;
    ay += (double)fu.y * sc;
  }
  double dn = dn64[v];
  double info = fabs((double)f.x - ax * dn) + fabs((double)f.y - ay * dn);
  double dot = (double)f.x * wa64[2 * lane] + (double)f.y * wa64[2 * lane + 1];
#pragma unroll
  for (int off = 32; off > 0; off >>= 1) {
    info += __shfl_down(info, off);
    dot  += __shfl_down(dot, off);
  }
  if (lane == 0) {
    double sA = dot >= 0.0 ? dot : 0.2 * dot;   // leaky_relu 0.2
    double attn = 1.0 / (1.0 + exp(-sA));
    double x = info * attn;
    out_xs[v] = (float)x;
    xs64[v] = x;
  }
}

// ---- per-graph top-K via bitonic sort of (val desc, idx asc) pairs ----
__global__ void k_topk(const double* __restrict__ xs64, float* __restrict__ out_perm,
                       int* __restrict__ perm_i, int* __restrict__ maskarr) {
  __shared__ double dv[1024];
  __shared__ int di[1024];
  int b = blockIdx.x, t = threadIdx.x;
  for (int i = t; i < 1024; i += 256) { dv[i] = xs64[b * 1024 + i]; di[i] = i; }
  __syncthreads();
  for (int k2 = 2; k2 <= 1024; k2 <<= 1) {
    for (int j = k2 >> 1; j > 0; j >>= 1) {
      for (int i = t; i < 1024; i += 256) {
        int ixj = i ^ j;
        if (ixj > i) {
          double a = dv[i], c = dv[ixj];
          int ia = di[i], ic = di[ixj];
          bool pre = (a > c) || (a == c && ia < ic);   // a precedes c in desc order
          bool dir = ((i & k2) == 0);                  // true -> descending segment
          if (pre != dir) { dv[i] = c; dv[ixj] = a; di[i] = ic; di[ixj] = ia; }
        }
      }
      __syncthreads();
    }
  }
  for (int r = t; r < K_; r += 256) {
    int node = b * N_ + di[r];
    int pos = b * K_ + r;
    out_perm[pos] = (float)node;    // output buffer is float32 view
    perm_i[pos] = node;
    maskarr[node] = pos;
  }
}

// ---- gather feat_p + wsrc/wdst dots (one wave per pooled row) ----
__global__ void k_gather(const float* __restrict__ feat, const int* __restrict__ perm_i,
                         const float* __restrict__ att, float* __restrict__ out_featp,
                         float* __restrict__ wsrc, float* __restrict__ wdst) {
  int gid = blockIdx.x * 256 + threadIdx.x;
  int p = gid >> 6, lane = gid & 63;
  int node = perm_i[p];
  float2 f = ((const float2*)feat)[(size_t)node * 64 + lane];
  ((float2*)out_featp)[(size_t)p * 64 + lane] = f;
  double s1 = (double)f.x * (double)att[2 * lane] + (double)f.y * (double)att[2 * lane + 1];
  double s2 = (double)f.x * (double)att[D_ + 2 * lane] + (double)f.y * (double)att[D_ + 2 * lane + 1];
#pragma unroll
  for (int off = 32; off > 0; off >>= 1) {
    s1 += __shfl_down(s1, off);
    s2 += __shfl_down(s2, off);
  }
  if (lane == 0) { wsrc[p] = (float)s1; wdst[p] = (float)s2; }
}

// ---- pooled-subgraph edge CSR keyed by pooled dst column ----
__global__ void k_cnt2(const int* __restrict__ src, const int* __restrict__ dst,
                       const int* __restrict__ maskarr, int* __restrict__ cnt2) {
  int e = blockIdx.x * 256 + threadIdx.x;
  int nr = maskarr[src[e]], nc = maskarr[dst[e]];
  if (nr >= 0 && nc >= 0) atomicAdd(&cnt2[nc], 1);
}

__global__ void k_fill2(const int* __restrict__ src, const int* __restrict__ dst,
                        const int* __restrict__ maskarr, const float* __restrict__ e_feat,
                        const int* __restrict__ rowptr2, int* __restrict__ cursor2,
                        int* __restrict__ colii, float* __restrict__ colval) {
  int e = blockIdx.x * 256 + threadIdx.x;
  int nr = maskarr[src[e]], nc = maskarr[dst[e]];
  if (nr >= 0 && nc >= 0) {
    int p = atomicAdd(&cursor2[nc], 1);
    int s = rowptr2[nc] + p;
    colii[s] = nr;                 // global pooled src index (b*K + i)
    colval[s] = 1.0f * e_feat[e];  // LAMB = 1
  }
}

// ---- dedupe duplicate (i,j) edges per column (must sum E before nonlinear clip) ----
__global__ void k_dedupe(const int* __restrict__ rowptr2, int* __restrict__ colii,
                         float* __restrict__ colval, int* __restrict__ ucnt) {
  int c = blockIdx.x * 256 + threadIdx.x;
  int r0 = rowptr2[c], r1 = rowptr2[c + 1];
  int w = r0;
  for (int s = r0; s < r1; ++s) {
    int ii = colii[s];
    if (ii < 0) continue;
    float E = colval[s];
    for (int t2 = s + 1; t2 < r1; ++t2)
      if (colii[t2] == ii) { E += colval[t2]; colii[t2] = -1; }
    colii[w] = ii; colval[w] = E; ++w;
  }
  ucnt[c] = w - r0;
}

// ---- per-graph sort of wsrc (desc) + prefix sums ----
__global__ void k_gsort(const float* __restrict__ wsrc, float* __restrict__ ws_sorted,
                        float* __restrict__ psum) {
  __shared__ float sv[1024];
  __shared__ float sc[1024];
  int b = blockIdx.x, t = threadIdx.x;
  for (int i = t; i < 1024; i += 256) sv[i] = (i < K_) ? wsrc[b * K_ + i] : -INFINITY;
  __syncthreads();
  for (int k2 = 2; k2 <= 1024; k2 <<= 1) {
    for (int j = k2 >> 1; j > 0; j >>= 1) {
      for (int i = t; i < 1024; i += 256) {
        int ixj = i ^ j;
        if (ixj > i) {
          float a = sv[i], c = sv[ixj];
          bool dir = ((i & k2) == 0);
          bool swapv = dir ? (c > a) : (a > c);
          if (swapv) { sv[i] = c; sv[ixj] = a; }
        }
      }
      __syncthreads();
    }
  }
  for (int i = t; i < 1024; i += 256) { ws_sorted[b * 1024 + i] = sv[i]; sc[i] = sv[i]; }
  __syncthreads();
  for (int off = 1; off < 1024; off <<= 1) {
    float tmp[4];
    for (int i = t, q = 0; i < 1024; i += 256, ++q) tmp[q] = (i >= off) ? sc[i - off] : 0.f;
    __syncthreads();
    for (int i = t, q = 0; i < 1024; i += 256, ++q) sc[i] += tmp[q];
    __syncthreads();
  }
  if (t == 0) psum[b * 1025] = 0.f;
  for (int i = t; i < 1024; i += 256) psum[b * 1025 + 1 + i] = sc[i];
}

// count of entries > thr in desc-sorted LDS array, searching index range [lo,hi)
__device__ __forceinline__ int cnt_gt_rng(const float* __restrict__ arr, float thr,
                                          int lo, int hi) {
  while (lo < hi) {
    int mid = (lo + hi) >> 1;
    if (arr[mid] > thr) lo = mid + 1; else hi = mid;
  }
  return lo;
}

// ---- tau per column via bisection on g(t) = sum max(z-t,0) = 1 ----
// LDS-staged per-graph sorted wsrc + prefix sums; shrinking [nmin,nmax] support
// bracket cuts the dependent binary-search chain ~5x; sparse entries preloaded.
// Same math as round 2 (which passed): identical-predicate cancel + [mz-1,mz] clamp.
__global__ void __launch_bounds__(64) k_tau(
    const float* __restrict__ wsrc, const float* __restrict__ wdst,
    const float* __restrict__ ws_sorted, const float* __restrict__ psum,
    const int* __restrict__ rowptr2, const int* __restrict__ ucnt,
    const int* __restrict__ colii, const float* __restrict__ colval,
    float* __restrict__ tauv) {
  __shared__ float swss[1024];
  __shared__ float sps[1025];
  int b = blockIdx.x / CPB_;
  int chunk = blockIdx.x % CPB_;
  int t0 = threadIdx.x;
  for (int i = t0; i < 1024; i += 64) swss[i] = ws_sorted[b * 1024 + i];
  for (int i = t0; i < 1025; i += 64) sps[i] = psum[b * 1025 + i];
  __syncthreads();

  int j = chunk * CH_ + t0;
  if (t0 >= CH_ || j >= K_) return;
  int c = b * K_ + j;

  float wd = wdst[c];
  int p = cnt_gt_rng(swss, -wd, 0, K_);
  float psp = sps[p];
  int r0 = rowptr2[c], m = ucnt[c];
  int mm = m < MAXM_ ? m : MAXM_;

  float a_ws[MAXM_], a_b[MAXM_], a_e[MAXM_];
  for (int s = 0; s < mm; ++s) {
    float w = wsrc[colii[r0 + s]];
    a_ws[s] = w;
    a_b[s] = lrelu(w + wd);
    a_e[s] = colval[r0 + s];
  }

  float mz = lrelu(swss[0] + wd);
  for (int s = 0; s < mm; ++s) mz = fmaxf(mz, a_b[s] + a_e[s]);
  for (int s = mm; s < m; ++s)                     // rare overflow fallback
    mz = fmaxf(mz, lrelu(wsrc[colii[r0 + s]] + wd) + colval[r0 + s]);

  float lo = mz - 1.0f, hi = mz;                   // g(mz)=0<1, g(mz-1)>=1
  int nmin = 0, nmax = K_;                         // support-count bracket
  for (int it = 0; it < 32; ++it) {
    float t = 0.5f * (lo + hi);
    float wthr = (t >= 0.f ? t : 5.f * t) - wd;
    int n = cnt_gt_rng(swss, wthr, nmin, nmax);
    float bsum = (n <= p) ? (sps[n] + n * wd)
                          : (psp + p * wd + NEG_ * (sps[n] - psp + (n - p) * wd));
    float g = bsum - n * t;
    for (int s = 0; s < mm; ++s)
      g += fmaxf(a_b[s] + a_e[s] - t, 0.f) - fmaxf(a_b[s] - t, 0.f);
    for (int s = mm; s < m; ++s) {
      float bse = lrelu(wsrc[colii[r0 + s]] + wd);
      g += fmaxf(bse + colval[r0 + s] - t, 0.f) - fmaxf(bse - t, 0.f);
    }
    if (g > 1.f) { lo = t; nmax = n; } else { hi = t; nmin = n; }
  }
  float t = lo;                                    // t <= tau*, within ~2^-32 of it
  float wthr = (t >= 0.f ? t : 5.f * t) - wd;
  int n = cnt_gt_rng(swss, wthr, nmin, nmax);
  float S = (n <= p) ? (sps[n] + n * wd)
                     : (psp + p * wd + NEG_ * (sps[n] - psp + (n - p) * wd));
  int cc = n;
  for (int s = 0; s < mm; ++s) {
    float zz = a_b[s] + a_e[s];
    if (a_ws[s] > wthr) { S -= a_b[s]; cc -= 1; }  // same predicate as cnt -> exact cancel
    if (zz > t)         { S += zz;     cc += 1; }
  }
  for (int s = mm; s < m; ++s) {
    float ws_i = wsrc[colii[r0 + s]];
    float bse = lrelu(ws_i + wd);
    float zz = bse + colval[r0 + s];
    if (ws_i > wthr) { S -= bse; cc -= 1; }
    if (zz > t)      { S += zz;  cc += 1; }
  }
  float tau = (cc < 1) ? (mz - 1.0f) : ((S - 1.0f) / (float)cc);
  tau = fminf(fmaxf(tau, mz - 1.0f), mz);          // true tau* in [mz-1, mz)
  tauv[c] = tau;
}

// ---- dense weights: coalesced j-fastest, ignores sparse E (fixed up next) ----
__global__ void k_dense(const float* __restrict__ wsrc, const float* __restrict__ wdst,
                        const float* __restrict__ tauv, float* __restrict__ out_w) {
  int j = blockIdx.x * 256 + threadIdx.x;
  if (j >= K_) return;
  int row = blockIdx.y;                         // b*K + i
  int b = row / K_;
  int c = b * K_ + j;
  float z = lrelu(wsrc[row] + wdst[c]);
  float v = z - tauv[c];
  out_w[(size_t)row * K_ + j] = (v > 1e-9f) ? v : 0.f;
}

// ---- rewrite the edge-perturbed entries with the correct value ----
__global__ void k_fix(const float* __restrict__ wsrc, const float* __restrict__ wdst,
                      const float* __restrict__ tauv, const int* __restrict__ rowptr2,
                      const int* __restrict__ ucnt, const int* __restrict__ colii,
                      const float* __restrict__ colval, float* __restrict__ out_w) {
  int c = blockIdx.x * 256 + threadIdx.x;
  int b = c / K_;
  int j = c - b * K_;
  float wd = wdst[c], ta = tauv[c];
  int r0 = rowptr2[c], m = ucnt[c];
  for (int s = 0; s < m; ++s) {
    int nr = colii[r0 + s];
    float z = lrelu(wsrc[nr] + wd) + colval[r0 + s];
    float v = z - ta;
    out_w[(size_t)nr * K_ + j] = (v > 1e-9f) ? v : 0.f;
  }
}

extern "C" void kernel_launch(void* const* d_in, const int* in_sizes, int n_in,
                              void* d_out, int out_size, void* d_ws, size_t ws_size,
                              hipStream_t stream) {
  const float* feat   = (const float*)d_in[0];
  const float* e_feat = (const float*)d_in[1];
  const float* W      = (const float*)d_in[2];
  const float* a      = (const float*)d_in[3];
  const float* att    = (const float*)d_in[4];
  const int*   src    = (const int*)d_in[5];
  const int*   dst    = (const int*)d_in[6];

  float* out_featp = (float*)d_out;                       // [BK*D]
  float* out_w     = out_featp + (size_t)BK_ * D_;        // [BK*K]
  float* out_perm  = out_w + (size_t)BK_ * K_;            // [BK]
  float* out_xs    = out_perm + BK_;                      // [NTOT]

  char* wsp = (char*)d_ws;
  auto carve = [&](size_t bytes) -> void* {
    void* pp = (void*)wsp;
    wsp += (bytes + 255) & ~(size_t)255;
    return pp;
  };
  double* xs64     = (double*)carve((size_t)NTOT_ * 8);
  double* wa64     = (double*)carve((size_t)D_ * 8);
  double* sn64     = (double*)carve((size_t)NTOT_ * 8);
  double* dn64     = (double*)carve((size_t)NTOT_ * 8);
  float* wsrc      = (float*)carve((size_t)BK_ * 4);
  float* wdst      = (float*)carve((size_t)BK_ * 4);
  float* tauv      = (float*)carve((size_t)BK_ * 4);
  float* colval    = (float*)carve((size_t)ETOT_ * 4);
  float* ws_sorted = (float*)carve((size_t)B_ * 1024 * 4);
  float* psum      = (float*)carve((size_t)B_ * 1025 * 4);
  int* rowptr      = (int*)carve((size_t)(NTOT_ + 1) * 4);
  int* rowptr2     = (int*)carve((size_t)(BK_ + 1) * 4);
  int* col         = (int*)carve((size_t)ETOT_ * 4);
  int* colii       = (int*)carve((size_t)ETOT_ * 4);
  int* perm_i      = (int*)carve((size_t)BK_ * 4);
  size_t zbytes    = ((size_t)NTOT_ * 3 + (size_t)BK_ * 2) * 4;
  int* zblk        = (int*)carve(zbytes);
  int* in_deg      = zblk;
  int* out_deg     = zblk + NTOT_;
  int* cursor      = zblk + 2 * NTOT_;
  int* cnt2        = zblk + 3 * NTOT_;
  int* cursor2     = cnt2 + BK_;
  int* maskarr     = (int*)carve((size_t)NTOT_ * 4);

  hipMemsetAsync(zblk, 0, zbytes, stream);
  hipMemsetAsync(maskarr, 0xFF, (size_t)NTOT_ * 4, stream);   // -1

  k_wa<<<1, 128, 0, stream>>>(W, a, wa64);
  k_deg<<<ETOT_ / 256, 256, 0, stream>>>(src, dst, out_deg, in_deg);
  k_scale<<<NTOT_ / 256, 256, 0, stream>>>(out_deg, in_deg, sn64, dn64);
  k_exscan<<<1, 1024, 0, stream>>>(in_deg, rowptr, NTOT_);
  k_fillcsr<<<ETOT_ / 256, 256, 0, stream>>>(dst, rowptr, cursor, col);
  k_agg<<<NTOT_ / 4, 256, 0, stream>>>(feat, e_feat, src, col, rowptr, sn64, dn64,
                                       wa64, out_xs, xs64);
  k_topk<<<B_, 256, 0, stream>>>(xs64, out_perm, perm_i, maskarr);
  k_gather<<<BK_ / 4, 256, 0, stream>>>(feat, perm_i, att, out_featp, wsrc, wdst);
  k_cnt2<<<ETOT_ / 256, 256, 0, stream>>>(src, dst, maskarr, cnt2);
  k_exscan<<<1, 1024, 0, stream>>>(cnt2, rowptr2, BK_);
  k_fill2<<<ETOT_ / 256, 256, 0, stream>>>(src, dst, maskarr, e_feat, rowptr2, cursor2,
                                           colii, colval);
  k_dedupe<<<BK_ / 256, 256, 0, stream>>>(rowptr2, colii, colval, cursor2);
  k_gsort<<<B_, 256, 0, stream>>>(wsrc, ws_sorted, psum);
  k_tau<<<B_ * CPB_, 64, 0, stream>>>(wsrc, wdst, ws_sorted, psum, rowptr2, cursor2,
                                      colii, colval, tauv);
  k_dense<<<dim3(4, BK_), 256, 0, stream>>>(wsrc, wdst, tauv, out_w);
  k_fix<<<BK_ / 256, 256, 0, stream>>>(wsrc, wdst, tauv, rowptr2, cursor2, colii, colval,
                                       out_w);
}

// Round 4
// 886.602 us; speedup vs baseline: 1.0632x; 1.0391x over previous
//
#include <hip/hip_runtime.h>
#include <math.h>

// HGPSLPool: B=64 graphs, N=1024 nodes, D=128, EPG=8192, K=820.
// Outputs (concat, float32 view): feat_p [B*K*D], weights [B*K*K], perm [B*K], x_score [NTOT].

static constexpr int B_    = 64;
static constexpr int N_    = 1024;
static constexpr int D_    = 128;
static constexpr int NTOT_ = B_ * N_;     // 65536
static constexpr int ETOT_ = B_ * 8192;   // 524288
static constexpr int K_    = 820;
static constexpr int BK_   = B_ * K_;     // 52480
static constexpr float NEG_ = 0.2f;
static constexpr int CH_   = 128;         // k_tau: columns per block (all threads active)
static constexpr int CPB_  = 7;           // chunks per graph (7*128=896 >= 820)

__device__ __forceinline__ float lrelu(float x) { return x >= 0.f ? x : NEG_ * x; }

// ---- wa = W @ a (fp64), 1 block x 128 ----
__global__ void k_wa(const float* __restrict__ W, const float* __restrict__ a,
                     double* __restrict__ wa64) {
  int d = threadIdx.x;
  double s = 0.0;
  for (int k = 0; k < D_; ++k) s += (double)W[d * D_ + k] * (double)a[k];
  wa64[d] = s;
}

// ---- degrees (self-loops included, matching ref) ----
__global__ void k_deg(const int* __restrict__ src, const int* __restrict__ dst,
                      int* __restrict__ outd, int* __restrict__ ind) {
  int e = blockIdx.x * 256 + threadIdx.x;
  atomicAdd(&outd[src[e]], 1);
  atomicAdd(&ind[dst[e]], 1);
}

// ---- per-node symmetric-norm scales (lane-invariant work hoisted out of k_agg) ----
__global__ void k_scale(const int* __restrict__ outd, const int* __restrict__ ind,
                        double* __restrict__ sn64, double* __restrict__ dn64) {
  int v = blockIdx.x * 256 + threadIdx.x;
  sn64[v] = 1.0 / sqrt(fmax((double)outd[v], 1.0));
  dn64[v] = 1.0 / sqrt(fmax((double)ind[v], 1.0));
}

// ---- exclusive scan, single block of 1024, thread-serial chunks ----
__global__ void k_exscan(const int* __restrict__ in, int* __restrict__ out, int n) {
  __shared__ int bs[1024];
  int t = threadIdx.x;
  int per = (n + 1023) >> 10;
  int s0 = t * per, s1 = min(s0 + per, n);
  int s = 0;
  for (int i = s0; i < s1; ++i) s += in[i];
  bs[t] = s;
  __syncthreads();
  for (int off = 1; off < 1024; off <<= 1) {
    int v = (t >= off) ? bs[t - off] : 0;
    __syncthreads();
    bs[t] += v;
    __syncthreads();
  }
  int base = (t == 0) ? 0 : bs[t - 1];
  for (int i = s0; i < s1; ++i) { out[i] = base; base += in[i]; }
  if (t == 1023) out[n] = base;
}

// ---- fill dst-CSR ----
__global__ void k_fillcsr(const int* __restrict__ dst, const int* __restrict__ rowptr,
                          int* __restrict__ cursor, int* __restrict__ col) {
  int e = blockIdx.x * 256 + threadIdx.x;
  int v = dst[e];
  int p = atomicAdd(&cursor[v], 1);
  col[rowptr[v] + p] = e;
}

// ---- neighbor aggregation + info + attn + x_score (fp64 for top-k ordering) ----
// one wave per node; lane holds dims 2l, 2l+1
__global__ void k_agg(const float* __restrict__ feat, const float* __restrict__ e_feat,
                      const int* __restrict__ src, const int* __restrict__ col,
                      const int* __restrict__ rowptr, const double* __restrict__ sn64,
                      const double* __restrict__ dn64, const double* __restrict__ wa64,
                      float* __restrict__ out_xs, double* __restrict__ xs64) {
  int gid = blockIdx.x * 256 + threadIdx.x;
  int v = gid >> 6, lane = gid & 63;
  const float2* f2 = (const float2*)feat;
  float2 f = f2[(size_t)v * 64 + lane];
  double ax = 0.0, ay = 0.0;
  int r0 = rowptr[v], r1 = rowptr[v + 1];
  for (int sP = r0; sP < r1; ++sP) {
    int e = col[sP];
    int u = src[e];
    if (u == v) continue;                       // remove_self_loop for messages
    double sc = (double)e_feat[e] * sn64[u];
    float2 fu = f2[(size_t)u * 64 + lane];
    ax += (double)fu.x * sc;
    ay += (double)fu.y * sc;
  }
  double dn = dn64[v];
  double info = fabs((double)f.x - ax * dn) + fabs((double)f.y - ay * dn);
  double dot = (double)f.x * wa64[2 * lane] + (double)f.y * wa64[2 * lane + 1];
#pragma unroll
  for (int off = 32; off > 0; off >>= 1) {
    info += __shfl_down(info, off);
    dot  += __shfl_down(dot, off);
  }
  if (lane == 0) {
    double sA = dot >= 0.0 ? dot : 0.2 * dot;   // leaky_relu 0.2
    double attn = 1.0 / (1.0 + exp(-sA));
    double x = info * attn;
    out_xs[v] = (float)x;
    xs64[v] = x;
  }
}

// ---- per-graph top-K via bitonic sort of (val desc, idx asc) pairs ----
__global__ void k_topk(const double* __restrict__ xs64, float* __restrict__ out_perm,
                       int* __restrict__ perm_i, int* __restrict__ maskarr) {
  __shared__ double dv[1024];
  __shared__ int di[1024];
  int b = blockIdx.x, t = threadIdx.x;
  for (int i = t; i < 1024; i += 256) { dv[i] = xs64[b * 1024 + i]; di[i] = i; }
  __syncthreads();
  for (int k2 = 2; k2 <= 1024; k2 <<= 1) {
    for (int j = k2 >> 1; j > 0; j >>= 1) {
      for (int i = t; i < 1024; i += 256) {
        int ixj = i ^ j;
        if (ixj > i) {
          double a = dv[i], c = dv[ixj];
          int ia = di[i], ic = di[ixj];
          bool pre = (a > c) || (a == c && ia < ic);   // a precedes c in desc order
          bool dir = ((i & k2) == 0);                  // true -> descending segment
          if (pre != dir) { dv[i] = c; dv[ixj] = a; di[i] = ic; di[ixj] = ia; }
        }
      }
      __syncthreads();
    }
  }
  for (int r = t; r < K_; r += 256) {
    int node = b * N_ + di[r];
    int pos = b * K_ + r;
    out_perm[pos] = (float)node;    // output buffer is float32 view
    perm_i[pos] = node;
    maskarr[node] = pos;
  }
}

// ---- gather feat_p + wsrc/wdst dots (one wave per pooled row) ----
__global__ void k_gather(const float* __restrict__ feat, const int* __restrict__ perm_i,
                         const float* __restrict__ att, float* __restrict__ out_featp,
                         float* __restrict__ wsrc, float* __restrict__ wdst) {
  int gid = blockIdx.x * 256 + threadIdx.x;
  int p = gid >> 6, lane = gid & 63;
  int node = perm_i[p];
  float2 f = ((const float2*)feat)[(size_t)node * 64 + lane];
  ((float2*)out_featp)[(size_t)p * 64 + lane] = f;
  double s1 = (double)f.x * (double)att[2 * lane] + (double)f.y * (double)att[2 * lane + 1];
  double s2 = (double)f.x * (double)att[D_ + 2 * lane] + (double)f.y * (double)att[D_ + 2 * lane + 1];
#pragma unroll
  for (int off = 32; off > 0; off >>= 1) {
    s1 += __shfl_down(s1, off);
    s2 += __shfl_down(s2, off);
  }
  if (lane == 0) { wsrc[p] = (float)s1; wdst[p] = (float)s2; }
}

// ---- pooled-subgraph edge CSR keyed by pooled dst column ----
__global__ void k_cnt2(const int* __restrict__ src, const int* __restrict__ dst,
                       const int* __restrict__ maskarr, int* __restrict__ cnt2) {
  int e = blockIdx.x * 256 + threadIdx.x;
  int nr = maskarr[src[e]], nc = maskarr[dst[e]];
  if (nr >= 0 && nc >= 0) atomicAdd(&cnt2[nc], 1);
}

__global__ void k_fill2(const int* __restrict__ src, const int* __restrict__ dst,
                        const int* __restrict__ maskarr, const float* __restrict__ e_feat,
                        const int* __restrict__ rowptr2, int* __restrict__ cursor2,
                        int* __restrict__ colii, float* __restrict__ colval) {
  int e = blockIdx.x * 256 + threadIdx.x;
  int nr = maskarr[src[e]], nc = maskarr[dst[e]];
  if (nr >= 0 && nc >= 0) {
    int p = atomicAdd(&cursor2[nc], 1);
    int s = rowptr2[nc] + p;
    colii[s] = nr;                 // global pooled src index (b*K + i)
    colval[s] = 1.0f * e_feat[e];  // LAMB = 1
  }
}

// ---- dedupe duplicate (i,j) edges per column + pre-gather (wsrc[ii], E) pairs ----
// bval[s] = (wsrc value of entry, deduped E) -- so k_tau never chases colii again.
__global__ void k_dedupe(const int* __restrict__ rowptr2, int* __restrict__ colii,
                         float* __restrict__ colval, int* __restrict__ ucnt,
                         const float* __restrict__ wsrc, float2* __restrict__ bval) {
  int c = blockIdx.x * 256 + threadIdx.x;
  int r0 = rowptr2[c], r1 = rowptr2[c + 1];
  int w = r0;
  for (int s = r0; s < r1; ++s) {
    int ii = colii[s];
    if (ii < 0) continue;
    float E = colval[s];
    for (int t2 = s + 1; t2 < r1; ++t2)
      if (colii[t2] == ii) { E += colval[t2]; colii[t2] = -1; }
    colii[w] = ii; colval[w] = E; ++w;
  }
  ucnt[c] = w - r0;
  for (int s = r0; s < w; ++s) bval[s] = make_float2(wsrc[colii[s]], colval[s]);
}

// ---- per-graph sort of wsrc (desc) + prefix sums ----
__global__ void k_gsort(const float* __restrict__ wsrc, float* __restrict__ ws_sorted,
                        float* __restrict__ psum) {
  __shared__ float sv[1024];
  __shared__ float sc[1024];
  int b = blockIdx.x, t = threadIdx.x;
  for (int i = t; i < 1024; i += 256) sv[i] = (i < K_) ? wsrc[b * K_ + i] : -INFINITY;
  __syncthreads();
  for (int k2 = 2; k2 <= 1024; k2 <<= 1) {
    for (int j = k2 >> 1; j > 0; j >>= 1) {
      for (int i = t; i < 1024; i += 256) {
        int ixj = i ^ j;
        if (ixj > i) {
          float a = sv[i], c = sv[ixj];
          bool dir = ((i & k2) == 0);
          bool swapv = dir ? (c > a) : (a > c);
          if (swapv) { sv[i] = c; sv[ixj] = a; }
        }
      }
      __syncthreads();
    }
  }
  for (int i = t; i < 1024; i += 256) { ws_sorted[b * 1024 + i] = sv[i]; sc[i] = sv[i]; }
  __syncthreads();
  for (int off = 1; off < 1024; off <<= 1) {
    float tmp[4];
    for (int i = t, q = 0; i < 1024; i += 256, ++q) tmp[q] = (i >= off) ? sc[i - off] : 0.f;
    __syncthreads();
    for (int i = t, q = 0; i < 1024; i += 256, ++q) sc[i] += tmp[q];
    __syncthreads();
  }
  if (t == 0) psum[b * 1025] = 0.f;
  for (int i = t; i < 1024; i += 256) psum[b * 1025 + 1 + i] = sc[i];
}

// count of entries > thr in desc-sorted LDS array, searching index range [lo,hi)
__device__ __forceinline__ int cnt_gt_rng(const float* __restrict__ arr, float thr,
                                          int lo, int hi) {
  while (lo < hi) {
    int mid = (lo + hi) >> 1;
    if (arr[mid] > thr) lo = mid + 1; else hi = mid;
  }
  return lo;
}

// ---- tau per column via bisection on g(t) = sum max(z-t,0) = 1 ----
// LDS-staged sorted wsrc + prefix sums; shrinking [nmin,nmax] support bracket.
// Sparse entries read as contiguous L2-hot float2 (NO private arrays -> no scratch).
// Math identical to the round-2 passing version (predicate-matched cancel + clamp).
__global__ void __launch_bounds__(128) k_tau(
    const float* __restrict__ wdst,
    const float* __restrict__ ws_sorted, const float* __restrict__ psum,
    const int* __restrict__ rowptr2, const int* __restrict__ ucnt,
    const float2* __restrict__ bval, float* __restrict__ tauv) {
  __shared__ float swss[1024];
  __shared__ float sps[1025];
  int b = blockIdx.x / CPB_;
  int chunk = blockIdx.x % CPB_;
  int t0 = threadIdx.x;
  for (int i = t0; i < 1024; i += 128) swss[i] = ws_sorted[b * 1024 + i];
  for (int i = t0; i < 1025; i += 128) sps[i] = psum[b * 1025 + i];
  __syncthreads();

  int j = chunk * CH_ + t0;
  if (j >= K_) return;
  int c = b * K_ + j;

  float wd = wdst[c];
  int p = cnt_gt_rng(swss, -wd, 0, K_);
  float psp = sps[p];
  int r0 = rowptr2[c], m = ucnt[c];

  float mz = lrelu(swss[0] + wd);
  for (int s = 0; s < m; ++s) {
    float2 v = bval[r0 + s];
    mz = fmaxf(mz, lrelu(v.x + wd) + v.y);       // E > 0 (e_feat=1, LAMB=1)
  }

  float lo = mz - 1.0f, hi = mz;                 // g(mz)=0<1, g(mz-1)>=1
  int nmin = 0, nmax = K_;                       // support-count bracket
  for (int it = 0; it < 22; ++it) {
    float t = 0.5f * (lo + hi);
    float wthr = (t >= 0.f ? t : 5.f * t) - wd;
    int n = cnt_gt_rng(swss, wthr, nmin, nmax);
    float bsum = (n <= p) ? (sps[n] + n * wd)
                          : (psp + p * wd + NEG_ * (sps[n] - psp + (n - p) * wd));
    float g = bsum - n * t;
    for (int s = 0; s < m; ++s) {
      float2 v = bval[r0 + s];
      float bse = lrelu(v.x + wd);
      g += fmaxf(bse + v.y - t, 0.f) - fmaxf(bse - t, 0.f);
    }
    if (g > 1.f) { lo = t; nmax = n; } else { hi = t; nmin = n; }
  }
  float t = lo;                                  // t <= tau*, bracket ~2.4e-7
  float wthr = (t >= 0.f ? t : 5.f * t) - wd;
  int n = cnt_gt_rng(swss, wthr, nmin, nmax);
  float S = (n <= p) ? (sps[n] + n * wd)
                     : (psp + p * wd + NEG_ * (sps[n] - psp + (n - p) * wd));
  int cc = n;
  for (int s = 0; s < m; ++s) {
    float2 v = bval[r0 + s];
    float bse = lrelu(v.x + wd);
    float zz = bse + v.y;
    if (v.x > wthr) { S -= bse; cc -= 1; }       // same predicate as cnt -> exact cancel
    if (zz > t)     { S += zz;  cc += 1; }
  }
  float tau = (cc < 1) ? (mz - 1.0f) : ((S - 1.0f) / (float)cc);
  tau = fminf(fmaxf(tau, mz - 1.0f), mz);        // true tau* in [mz-1, mz)
  tauv[c] = tau;
}

// ---- dense weights: coalesced j-fastest, ignores sparse E (fixed up next) ----
__global__ void k_dense(const float* __restrict__ wsrc, const float* __restrict__ wdst,
                        const float* __restrict__ tauv, float* __restrict__ out_w) {
  int j = blockIdx.x * 256 + threadIdx.x;
  if (j >= K_) return;
  int row = blockIdx.y;                         // b*K + i
  int b = row / K_;
  int c = b * K_ + j;
  float z = lrelu(wsrc[row] + wdst[c]);
  float v = z - tauv[c];
  out_w[(size_t)row * K_ + j] = (v > 1e-9f) ? v : 0.f;
}

// ---- rewrite the edge-perturbed entries with the correct value ----
__global__ void k_fix(const float* __restrict__ wsrc, const float* __restrict__ wdst,
                      const float* __restrict__ tauv, const int* __restrict__ rowptr2,
                      const int* __restrict__ ucnt, const int* __restrict__ colii,
                      const float* __restrict__ colval, float* __restrict__ out_w) {
  int c = blockIdx.x * 256 + threadIdx.x;
  int b = c / K_;
  int j = c - b * K_;
  float wd = wdst[c], ta = tauv[c];
  int r0 = rowptr2[c], m = ucnt[c];
  for (int s = 0; s < m; ++s) {
    int nr = colii[r0 + s];
    float z = lrelu(wsrc[nr] + wd) + colval[r0 + s];
    float v = z - ta;
    out_w[(size_t)nr * K_ + j] = (v > 1e-9f) ? v : 0.f;
  }
}

extern "C" void kernel_launch(void* const* d_in, const int* in_sizes, int n_in,
                              void* d_out, int out_size, void* d_ws, size_t ws_size,
                              hipStream_t stream) {
  const float* feat   = (const float*)d_in[0];
  const float* e_feat = (const float*)d_in[1];
  const float* W      = (const float*)d_in[2];
  const float* a      = (const float*)d_in[3];
  const float* att    = (const float*)d_in[4];
  const int*   src    = (const int*)d_in[5];
  const int*   dst    = (const int*)d_in[6];

  float* out_featp = (float*)d_out;                       // [BK*D]
  float* out_w     = out_featp + (size_t)BK_ * D_;        // [BK*K]
  float* out_perm  = out_w + (size_t)BK_ * K_;            // [BK]
  float* out_xs    = out_perm + BK_;                      // [NTOT]

  char* wsp = (char*)d_ws;
  auto carve = [&](size_t bytes) -> void* {
    void* pp = (void*)wsp;
    wsp += (bytes + 255) & ~(size_t)255;
    return pp;
  };
  double* xs64     = (double*)carve((size_t)NTOT_ * 8);
  double* wa64     = (double*)carve((size_t)D_ * 8);
  double* sn64     = (double*)carve((size_t)NTOT_ * 8);
  double* dn64     = (double*)carve((size_t)NTOT_ * 8);
  float* wsrc      = (float*)carve((size_t)BK_ * 4);
  float* wdst      = (float*)carve((size_t)BK_ * 4);
  float* tauv      = (float*)carve((size_t)BK_ * 4);
  float* colval    = (float*)carve((size_t)ETOT_ * 4);
  float2* bval     = (float2*)carve((size_t)ETOT_ * 8);
  float* ws_sorted = (float*)carve((size_t)B_ * 1024 * 4);
  float* psum      = (float*)carve((size_t)B_ * 1025 * 4);
  int* rowptr      = (int*)carve((size_t)(NTOT_ + 1) * 4);
  int* rowptr2     = (int*)carve((size_t)(BK_ + 1) * 4);
  int* col         = (int*)carve((size_t)ETOT_ * 4);
  int* colii       = (int*)carve((size_t)ETOT_ * 4);
  int* perm_i      = (int*)carve((size_t)BK_ * 4);
  size_t zbytes    = ((size_t)NTOT_ * 3 + (size_t)BK_ * 2) * 4;
  int* zblk        = (int*)carve(zbytes);
  int* in_deg      = zblk;
  int* out_deg     = zblk + NTOT_;
  int* cursor      = zblk + 2 * NTOT_;
  int* cnt2        = zblk + 3 * NTOT_;
  int* cursor2     = cnt2 + BK_;
  int* maskarr     = (int*)carve((size_t)NTOT_ * 4);

  hipMemsetAsync(zblk, 0, zbytes, stream);
  hipMemsetAsync(maskarr, 0xFF, (size_t)NTOT_ * 4, stream);   // -1

  k_wa<<<1, 128, 0, stream>>>(W, a, wa64);
  k_deg<<<ETOT_ / 256, 256, 0, stream>>>(src, dst, out_deg, in_deg);
  k_scale<<<NTOT_ / 256, 256, 0, stream>>>(out_deg, in_deg, sn64, dn64);
  k_exscan<<<1, 1024, 0, stream>>>(in_deg, rowptr, NTOT_);
  k_fillcsr<<<ETOT_ / 256, 256, 0, stream>>>(dst, rowptr, cursor, col);
  k_agg<<<NTOT_ / 4, 256, 0, stream>>>(feat, e_feat, src, col, rowptr, sn64, dn64,
                                       wa64, out_xs, xs64);
  k_topk<<<B_, 256, 0, stream>>>(xs64, out_perm, perm_i, maskarr);
  k_gather<<<BK_ / 4, 256, 0, stream>>>(feat, perm_i, att, out_featp, wsrc, wdst);
  k_cnt2<<<ETOT_ / 256, 256, 0, stream>>>(src, dst, maskarr, cnt2);
  k_exscan<<<1, 1024, 0, stream>>>(cnt2, rowptr2, BK_);
  k_fill2<<<ETOT_ / 256, 256, 0, stream>>>(src, dst, maskarr, e_feat, rowptr2, cursor2,
                                           colii, colval);
  k_dedupe<<<BK_ / 256, 256, 0, stream>>>(rowptr2, colii, colval, cursor2, wsrc, bval);
  k_gsort<<<B_, 256, 0, stream>>>(wsrc, ws_sorted, psum);
  k_tau<<<B_ * CPB_, 128, 0, stream>>>(wdst, ws_sorted, psum, rowptr2, cursor2,
                                       bval, tauv);
  k_dense<<<dim3(4, BK_), 256, 0, stream>>>(wsrc, wdst, tauv, out_w);
  k_fix<<<BK_ / 256, 256, 0, stream>>>(wsrc, wdst, tauv, rowptr2, cursor2, colii, colval,
                                       out_w);
}

// Round 5
// 753.710 us; speedup vs baseline: 1.2506x; 1.1763x over previous
//
#include <hip/hip_runtime.h>
#include <math.h>

// HGPSLPool: B=64 graphs, N=1024 nodes, D=128, EPG=8192, K=820.
// Outputs (concat, float32 view): feat_p [B*K*D], weights [B*K*K], perm [B*K], x_score [NTOT].

static constexpr int B_    = 64;
static constexpr int N_    = 1024;
static constexpr int D_    = 128;
static constexpr int NTOT_ = B_ * N_;     // 65536
static constexpr int ETOT_ = B_ * 8192;   // 524288
static constexpr int K_    = 820;
static constexpr int BK_   = B_ * K_;     // 52480
static constexpr float NEG_ = 0.2f;
static constexpr int CH_   = 128;         // k_tau: columns per block
static constexpr int CPB_  = 7;           // chunks per graph (7*128=896 >= 820)
static constexpr int CAP_  = 64;          // k_agg: staged edges per node (max in-deg ~30)

__device__ __forceinline__ float lrelu(float x) { return x >= 0.f ? x : NEG_ * x; }

// ---- wa = W @ a (fp64), 1 block x 128 ----
__global__ void k_wa(const float* __restrict__ W, const float* __restrict__ a,
                     double* __restrict__ wa64) {
  int d = threadIdx.x;
  double s = 0.0;
  for (int k = 0; k < D_; ++k) s += (double)W[d * D_ + k] * (double)a[k];
  wa64[d] = s;
}

// ---- degrees (self-loops included, matching ref) ----
__global__ void k_deg(const int* __restrict__ src, const int* __restrict__ dst,
                      int* __restrict__ outd, int* __restrict__ ind) {
  int e = blockIdx.x * 256 + threadIdx.x;
  atomicAdd(&outd[src[e]], 1);
  atomicAdd(&ind[dst[e]], 1);
}

// ---- exclusive scan, single block of 1024, thread-serial chunks ----
__global__ void k_exscan(const int* __restrict__ in, int* __restrict__ out, int n) {
  __shared__ int bs[1024];
  int t = threadIdx.x;
  int per = (n + 1023) >> 10;
  int s0 = t * per, s1 = min(s0 + per, n);
  int s = 0;
  for (int i = s0; i < s1; ++i) s += in[i];
  bs[t] = s;
  __syncthreads();
  for (int off = 1; off < 1024; off <<= 1) {
    int v = (t >= off) ? bs[t - off] : 0;
    __syncthreads();
    bs[t] += v;
    __syncthreads();
  }
  int base = (t == 0) ? 0 : bs[t - 1];
  for (int i = s0; i < s1; ++i) { out[i] = base; base += in[i]; }
  if (t == 1023) out[n] = base;
}

// ---- fill dst-CSR ----
__global__ void k_fillcsr(const int* __restrict__ dst, const int* __restrict__ rowptr,
                          int* __restrict__ cursor, int* __restrict__ col) {
  int e = blockIdx.x * 256 + threadIdx.x;
  int v = dst[e];
  int p = atomicAdd(&cursor[v], 1);
  col[rowptr[v] + p] = e;
}

// ---- neighbor aggregation + info + attn + x_score ----
// One wave per node (4 per block). Edge metadata (u, scale) staged into LDS by
// lane-parallel loads (breaks the col->src->deg dependent chain), then the
// accumulate loop issues independent coalesced 512B feat gathers.
__global__ void k_agg(const float* __restrict__ feat, const float* __restrict__ e_feat,
                      const int* __restrict__ src, const int* __restrict__ col,
                      const int* __restrict__ rowptr, const int* __restrict__ outd,
                      const int* __restrict__ ind, const double* __restrict__ wa64,
                      float* __restrict__ out_xs) {
  __shared__ int su[4][CAP_];
  __shared__ double ssc[4][CAP_];
  int w = threadIdx.x >> 6, lane = threadIdx.x & 63;
  int v = blockIdx.x * 4 + w;
  int r0 = rowptr[v], r1 = rowptr[v + 1];
  int m = r1 - r0;
  int mm = m < CAP_ ? m : CAP_;
  for (int s = lane; s < mm; s += 64) {
    int e = col[r0 + s];
    int u = src[e];
    double sc = (u == v) ? 0.0
                         : (double)e_feat[e] / sqrt(fmax((double)outd[u], 1.0));
    su[w][s] = u;
    ssc[w][s] = sc;
  }
  __syncthreads();
  const float2* f2 = (const float2*)feat;
  float2 f = f2[(size_t)v * 64 + lane];
  double ax = 0.0, ay = 0.0;
  for (int s = 0; s < mm; ++s) {
    double sc = ssc[w][s];
    int u = su[w][s];
    float2 fu = f2[(size_t)u * 64 + lane];
    ax += (double)fu.x * sc;
    ay += (double)fu.y * sc;
  }
  for (int s = r0 + CAP_; s < r1; ++s) {        // statistically never taken
    int e = col[s];
    int u = src[e];
    if (u == v) continue;
    double sc = (double)e_feat[e] / sqrt(fmax((double)outd[u], 1.0));
    float2 fu = f2[(size_t)u * 64 + lane];
    ax += (double)fu.x * sc;
    ay += (double)fu.y * sc;
  }
  double dn = 1.0 / sqrt(fmax((double)ind[v], 1.0));
  double info = fabs((double)f.x - ax * dn) + fabs((double)f.y - ay * dn);
  double dot = (double)f.x * wa64[2 * lane] + (double)f.y * wa64[2 * lane + 1];
#pragma unroll
  for (int off = 32; off > 0; off >>= 1) {
    info += __shfl_down(info, off);
    dot  += __shfl_down(dot, off);
  }
  if (lane == 0) {
    double sA = dot >= 0.0 ? dot : 0.2 * dot;   // leaky_relu 0.2
    double attn = 1.0 / (1.0 + exp(-sA));
    out_xs[v] = (float)(info * attn);
  }
}

// ---- per-graph top-K: bitonic sort of u64-packed (f32 value desc, idx asc) ----
// x >= 0 so IEEE bits order == numeric order. key = (bits<<32) | (N-1-idx).
__global__ void k_topk(const float* __restrict__ xs, float* __restrict__ out_perm,
                       int* __restrict__ perm_i, int* __restrict__ maskarr) {
  __shared__ unsigned long long dv[1024];
  int b = blockIdx.x, t = threadIdx.x;
  for (int i = t; i < 1024; i += 256) {
    unsigned bits = __float_as_uint(xs[b * 1024 + i]);
    dv[i] = ((unsigned long long)bits << 32) | (unsigned)(N_ - 1 - i);
  }
  __syncthreads();
  for (int k2 = 2; k2 <= 1024; k2 <<= 1) {
    for (int j = k2 >> 1; j > 0; j >>= 1) {
      for (int i = t; i < 1024; i += 256) {
        int ixj = i ^ j;
        if (ixj > i) {
          unsigned long long a = dv[i], c = dv[ixj];
          bool dir = ((i & k2) == 0);              // true -> descending segment
          if ((a > c) != dir) { dv[i] = c; dv[ixj] = a; }
        }
      }
      __syncthreads();
    }
  }
  for (int r = t; r < K_; r += 256) {
    int idx = N_ - 1 - (int)(dv[r] & 0xFFFFFFFFull);
    int node = b * N_ + idx;
    int pos = b * K_ + r;
    out_perm[pos] = (float)node;    // output buffer is float32 view
    perm_i[pos] = node;
    maskarr[node] = pos;
  }
}

// ---- gather feat_p + wsrc/wdst dots (one wave per pooled row) ----
__global__ void k_gather(const float* __restrict__ feat, const int* __restrict__ perm_i,
                         const float* __restrict__ att, float* __restrict__ out_featp,
                         float* __restrict__ wsrc, float* __restrict__ wdst) {
  int gid = blockIdx.x * 256 + threadIdx.x;
  int p = gid >> 6, lane = gid & 63;
  int node = perm_i[p];
  float2 f = ((const float2*)feat)[(size_t)node * 64 + lane];
  ((float2*)out_featp)[(size_t)p * 64 + lane] = f;
  double s1 = (double)f.x * (double)att[2 * lane] + (double)f.y * (double)att[2 * lane + 1];
  double s2 = (double)f.x * (double)att[D_ + 2 * lane] + (double)f.y * (double)att[D_ + 2 * lane + 1];
#pragma unroll
  for (int off = 32; off > 0; off >>= 1) {
    s1 += __shfl_down(s1, off);
    s2 += __shfl_down(s2, off);
  }
  if (lane == 0) { wsrc[p] = (float)s1; wdst[p] = (float)s2; }
}

// ---- pooled-subgraph edge CSR keyed by pooled dst column ----
__global__ void k_cnt2(const int* __restrict__ src, const int* __restrict__ dst,
                       const int* __restrict__ maskarr, int* __restrict__ cnt2) {
  int e = blockIdx.x * 256 + threadIdx.x;
  int nr = maskarr[src[e]], nc = maskarr[dst[e]];
  if (nr >= 0 && nc >= 0) atomicAdd(&cnt2[nc], 1);
}

__global__ void k_fill2(const int* __restrict__ src, const int* __restrict__ dst,
                        const int* __restrict__ maskarr, const float* __restrict__ e_feat,
                        const int* __restrict__ rowptr2, int* __restrict__ cursor2,
                        int* __restrict__ colii, float* __restrict__ colval) {
  int e = blockIdx.x * 256 + threadIdx.x;
  int nr = maskarr[src[e]], nc = maskarr[dst[e]];
  if (nr >= 0 && nc >= 0) {
    int p = atomicAdd(&cursor2[nc], 1);
    int s = rowptr2[nc] + p;
    colii[s] = nr;                 // global pooled src index (b*K + i)
    colval[s] = 1.0f * e_feat[e];  // LAMB = 1
  }
}

// ---- dedupe duplicate (i,j) edges per column + pre-gather (wsrc[ii], E) pairs ----
__global__ void k_dedupe(const int* __restrict__ rowptr2, int* __restrict__ colii,
                         float* __restrict__ colval, int* __restrict__ ucnt,
                         const float* __restrict__ wsrc, float2* __restrict__ bval) {
  int c = blockIdx.x * 256 + threadIdx.x;
  int r0 = rowptr2[c], r1 = rowptr2[c + 1];
  int w = r0;
  for (int s = r0; s < r1; ++s) {
    int ii = colii[s];
    if (ii < 0) continue;
    float E = colval[s];
    for (int t2 = s + 1; t2 < r1; ++t2)
      if (colii[t2] == ii) { E += colval[t2]; colii[t2] = -1; }
    colii[w] = ii; colval[w] = E; ++w;
  }
  ucnt[c] = w - r0;
  for (int s = r0; s < w; ++s) bval[s] = make_float2(wsrc[colii[s]], colval[s]);
}

// ---- per-graph sort of wsrc (desc) + prefix sums ----
__global__ void k_gsort(const float* __restrict__ wsrc, float* __restrict__ ws_sorted,
                        float* __restrict__ psum) {
  __shared__ float sv[1024];
  __shared__ float sc[1024];
  int b = blockIdx.x, t = threadIdx.x;
  for (int i = t; i < 1024; i += 256) sv[i] = (i < K_) ? wsrc[b * K_ + i] : -INFINITY;
  __syncthreads();
  for (int k2 = 2; k2 <= 1024; k2 <<= 1) {
    for (int j = k2 >> 1; j > 0; j >>= 1) {
      for (int i = t; i < 1024; i += 256) {
        int ixj = i ^ j;
        if (ixj > i) {
          float a = sv[i], c = sv[ixj];
          bool dir = ((i & k2) == 0);
          bool swapv = dir ? (c > a) : (a > c);
          if (swapv) { sv[i] = c; sv[ixj] = a; }
        }
      }
      __syncthreads();
    }
  }
  for (int i = t; i < 1024; i += 256) { ws_sorted[b * 1024 + i] = sv[i]; sc[i] = sv[i]; }
  __syncthreads();
  for (int off = 1; off < 1024; off <<= 1) {
    float tmp[4];
    for (int i = t, q = 0; i < 1024; i += 256, ++q) tmp[q] = (i >= off) ? sc[i - off] : 0.f;
    __syncthreads();
    for (int i = t, q = 0; i < 1024; i += 256, ++q) sc[i] += tmp[q];
    __syncthreads();
  }
  if (t == 0) psum[b * 1025] = 0.f;
  for (int i = t; i < 1024; i += 256) psum[b * 1025 + 1 + i] = sc[i];
}

// count of entries > thr in desc-sorted LDS array, searching index range [lo,hi)
__device__ __forceinline__ int cnt_gt_rng(const float* __restrict__ arr, float thr,
                                          int lo, int hi) {
  while (lo < hi) {
    int mid = (lo + hi) >> 1;
    if (arr[mid] > thr) lo = mid + 1; else hi = mid;
  }
  return lo;
}

// ---- tau per column via bisection on g(t) = sum max(z-t,0) = 1 ----
__global__ void __launch_bounds__(128) k_tau(
    const float* __restrict__ wdst,
    const float* __restrict__ ws_sorted, const float* __restrict__ psum,
    const int* __restrict__ rowptr2, const int* __restrict__ ucnt,
    const float2* __restrict__ bval, float* __restrict__ tauv) {
  __shared__ float swss[1024];
  __shared__ float sps[1025];
  int b = blockIdx.x / CPB_;
  int chunk = blockIdx.x % CPB_;
  int t0 = threadIdx.x;
  for (int i = t0; i < 1024; i += 128) swss[i] = ws_sorted[b * 1024 + i];
  for (int i = t0; i < 1025; i += 128) sps[i] = psum[b * 1025 + i];
  __syncthreads();

  int j = chunk * CH_ + t0;
  if (j >= K_) return;
  int c = b * K_ + j;

  float wd = wdst[c];
  int p = cnt_gt_rng(swss, -wd, 0, K_);
  float psp = sps[p];
  int r0 = rowptr2[c], m = ucnt[c];

  float mz = lrelu(swss[0] + wd);
  for (int s = 0; s < m; ++s) {
    float2 v = bval[r0 + s];
    mz = fmaxf(mz, lrelu(v.x + wd) + v.y);       // E > 0 (e_feat=1, LAMB=1)
  }

  float lo = mz - 1.0f, hi = mz;                 // g(mz)=0<1, g(mz-1)>=1
  int nmin = 0, nmax = K_;                       // support-count bracket
  for (int it = 0; it < 22; ++it) {
    float t = 0.5f * (lo + hi);
    float wthr = (t >= 0.f ? t : 5.f * t) - wd;
    int n = cnt_gt_rng(swss, wthr, nmin, nmax);
    float bsum = (n <= p) ? (sps[n] + n * wd)
                          : (psp + p * wd + NEG_ * (sps[n] - psp + (n - p) * wd));
    float g = bsum - n * t;
    for (int s = 0; s < m; ++s) {
      float2 v = bval[r0 + s];
      float bse = lrelu(v.x + wd);
      g += fmaxf(bse + v.y - t, 0.f) - fmaxf(bse - t, 0.f);
    }
    if (g > 1.f) { lo = t; nmax = n; } else { hi = t; nmin = n; }
  }
  float t = lo;                                  // t <= tau*, bracket ~2.4e-7
  float wthr = (t >= 0.f ? t : 5.f * t) - wd;
  int n = cnt_gt_rng(swss, wthr, nmin, nmax);
  float S = (n <= p) ? (sps[n] + n * wd)
                     : (psp + p * wd + NEG_ * (sps[n] - psp + (n - p) * wd));
  int cc = n;
  for (int s = 0; s < m; ++s) {
    float2 v = bval[r0 + s];
    float bse = lrelu(v.x + wd);
    float zz = bse + v.y;
    if (v.x > wthr) { S -= bse; cc -= 1; }       // same predicate as cnt -> exact cancel
    if (zz > t)     { S += zz;  cc += 1; }
  }
  float tau = (cc < 1) ? (mz - 1.0f) : ((S - 1.0f) / (float)cc);
  tau = fminf(fmaxf(tau, mz - 1.0f), mz);        // true tau* in [mz-1, mz)
  tauv[c] = tau;
}

// ---- dense weights: float4 per thread (820 = 205*4), coalesced dwordx4 ----
__global__ void k_dense(const float* __restrict__ wsrc, const float* __restrict__ wdst,
                        const float* __restrict__ tauv, float* __restrict__ out_w) {
  int t = threadIdx.x;
  int j4 = t * 4;
  if (j4 >= K_) return;
  int row = blockIdx.x;                         // b*K + i
  int b = row / K_;
  const float4* wd4 = (const float4*)(wdst + b * K_);
  const float4* ta4 = (const float4*)(tauv + b * K_);
  float ws = wsrc[row];
  float4 wd = wd4[t];
  float4 ta = ta4[t];
  float4 o;
  float z;
  z = lrelu(ws + wd.x) - ta.x; o.x = (z > 1e-9f) ? z : 0.f;
  z = lrelu(ws + wd.y) - ta.y; o.y = (z > 1e-9f) ? z : 0.f;
  z = lrelu(ws + wd.z) - ta.z; o.z = (z > 1e-9f) ? z : 0.f;
  z = lrelu(ws + wd.w) - ta.w; o.w = (z > 1e-9f) ? z : 0.f;
  ((float4*)(out_w + (size_t)row * K_))[t] = o;
}

// ---- rewrite the edge-perturbed entries with the correct value ----
__global__ void k_fix(const float* __restrict__ wsrc, const float* __restrict__ wdst,
                      const float* __restrict__ tauv, const int* __restrict__ rowptr2,
                      const int* __restrict__ ucnt, const int* __restrict__ colii,
                      const float* __restrict__ colval, float* __restrict__ out_w) {
  int c = blockIdx.x * 256 + threadIdx.x;
  int b = c / K_;
  int j = c - b * K_;
  float wd = wdst[c], ta = tauv[c];
  int r0 = rowptr2[c], m = ucnt[c];
  for (int s = 0; s < m; ++s) {
    int nr = colii[r0 + s];
    float z = lrelu(wsrc[nr] + wd) + colval[r0 + s];
    float v = z - ta;
    out_w[(size_t)nr * K_ + j] = (v > 1e-9f) ? v : 0.f;
  }
}

extern "C" void kernel_launch(void* const* d_in, const int* in_sizes, int n_in,
                              void* d_out, int out_size, void* d_ws, size_t ws_size,
                              hipStream_t stream) {
  const float* feat   = (const float*)d_in[0];
  const float* e_feat = (const float*)d_in[1];
  const float* W      = (const float*)d_in[2];
  const float* a      = (const float*)d_in[3];
  const float* att    = (const float*)d_in[4];
  const int*   src    = (const int*)d_in[5];
  const int*   dst    = (const int*)d_in[6];

  float* out_featp = (float*)d_out;                       // [BK*D]
  float* out_w     = out_featp + (size_t)BK_ * D_;        // [BK*K]
  float* out_perm  = out_w + (size_t)BK_ * K_;            // [BK]
  float* out_xs    = out_perm + BK_;                      // [NTOT]

  char* wsp = (char*)d_ws;
  auto carve = [&](size_t bytes) -> void* {
    void* pp = (void*)wsp;
    wsp += (bytes + 255) & ~(size_t)255;
    return pp;
  };
  double* wa64     = (double*)carve((size_t)D_ * 8);
  float* wsrc      = (float*)carve((size_t)BK_ * 4);
  float* wdst      = (float*)carve((size_t)BK_ * 4);
  float* tauv      = (float*)carve((size_t)BK_ * 4);
  float* colval    = (float*)carve((size_t)ETOT_ * 4);
  float2* bval     = (float2*)carve((size_t)ETOT_ * 8);
  float* ws_sorted = (float*)carve((size_t)B_ * 1024 * 4);
  float* psum      = (float*)carve((size_t)B_ * 1025 * 4);
  int* rowptr      = (int*)carve((size_t)(NTOT_ + 1) * 4);
  int* rowptr2     = (int*)carve((size_t)(BK_ + 1) * 4);
  int* col         = (int*)carve((size_t)ETOT_ * 4);
  int* colii       = (int*)carve((size_t)ETOT_ * 4);
  int* perm_i      = (int*)carve((size_t)BK_ * 4);
  size_t zbytes    = ((size_t)NTOT_ * 3 + (size_t)BK_ * 2) * 4;
  int* zblk        = (int*)carve(zbytes);
  int* in_deg      = zblk;
  int* out_deg     = zblk + NTOT_;
  int* cursor      = zblk + 2 * NTOT_;
  int* cnt2        = zblk + 3 * NTOT_;
  int* cursor2     = cnt2 + BK_;
  int* maskarr     = (int*)carve((size_t)NTOT_ * 4);

  hipMemsetAsync(zblk, 0, zbytes, stream);
  hipMemsetAsync(maskarr, 0xFF, (size_t)NTOT_ * 4, stream);   // -1

  k_wa<<<1, 128, 0, stream>>>(W, a, wa64);
  k_deg<<<ETOT_ / 256, 256, 0, stream>>>(src, dst, out_deg, in_deg);
  k_exscan<<<1, 1024, 0, stream>>>(in_deg, rowptr, NTOT_);
  k_fillcsr<<<ETOT_ / 256, 256, 0, stream>>>(dst, rowptr, cursor, col);
  k_agg<<<NTOT_ / 4, 256, 0, stream>>>(feat, e_feat, src, col, rowptr, out_deg, in_deg,
                                       wa64, out_xs);
  k_topk<<<B_, 256, 0, stream>>>(out_xs, out_perm, perm_i, maskarr);
  k_gather<<<BK_ / 4, 256, 0, stream>>>(feat, perm_i, att, out_featp, wsrc, wdst);
  k_cnt2<<<ETOT_ / 256, 256, 0, stream>>>(src, dst, maskarr, cnt2);
  k_exscan<<<1, 1024, 0, stream>>>(cnt2, rowptr2, BK_);
  k_fill2<<<ETOT_ / 256, 256, 0, stream>>>(src, dst, maskarr, e_feat, rowptr2, cursor2,
                                           colii, colval);
  k_dedupe<<<BK_ / 256, 256, 0, stream>>>(rowptr2, colii, colval, cursor2, wsrc, bval);
  k_gsort<<<B_, 256, 0, stream>>>(wsrc, ws_sorted, psum);
  k_tau<<<B_ * CPB_, 128, 0, stream>>>(wdst, ws_sorted, psum, rowptr2, cursor2,
                                       bval, tauv);
  k_dense<<<BK_, 256, 0, stream>>>(wsrc, wdst, tauv, out_w);
  k_fix<<<BK_ / 256, 256, 0, stream>>>(wsrc, wdst, tauv, rowptr2, cursor2, colii, colval,
                                       out_w);
}

// Round 6
// 570.247 us; speedup vs baseline: 1.6530x; 1.3217x over previous
//
#include <hip/hip_runtime.h>
#include <math.h>

// HGPSLPool: B=64 graphs, N=1024 nodes, D=128, EPG=8192, K=820.
// Outputs (concat, float32 view): feat_p [B*K*D], weights [B*K*K], perm [B*K], x_score [NTOT].

static constexpr int B_    = 64;
static constexpr int N_    = 1024;
static constexpr int D_    = 128;
static constexpr int NTOT_ = B_ * N_;     // 65536
static constexpr int ETOT_ = B_ * 8192;   // 524288
static constexpr int K_    = 820;
static constexpr int BK_   = B_ * K_;     // 52480
static constexpr float NEG_ = 0.2f;
static constexpr int CH_   = 128;         // k_tau: columns per block
static constexpr int CPB_  = 7;           // chunks per graph (7*128=896 >= 820)
static constexpr int CAP_  = 64;          // k_agg: staged edges per node (max in-deg ~30)

__device__ __forceinline__ float lrelu(float x) { return x >= 0.f ? x : NEG_ * x; }

// ---- wa = W @ a (fp64 accumulate, fp32 out), 1 block x 128 ----
__global__ void k_wa(const float* __restrict__ W, const float* __restrict__ a,
                     float* __restrict__ waf) {
  int d = threadIdx.x;
  double s = 0.0;
  for (int k = 0; k < D_; ++k) s += (double)W[d * D_ + k] * (double)a[k];
  waf[d] = (float)s;
}

// ---- degrees (self-loops included, matching ref) ----
__global__ void k_deg(const int* __restrict__ src, const int* __restrict__ dst,
                      int* __restrict__ outd, int* __restrict__ ind) {
  int e = blockIdx.x * 256 + threadIdx.x;
  atomicAdd(&outd[src[e]], 1);
  atomicAdd(&ind[dst[e]], 1);
}

// ---- parallel exclusive scan, phase 1: per-block (1024-elem chunk) sums ----
__global__ void k_scansum(const int* __restrict__ in, int n, int* __restrict__ bsum) {
  int blk = blockIdx.x, t = threadIdx.x;
  int base = blk * 1024 + t * 4;
  int s = 0;
#pragma unroll
  for (int q = 0; q < 4; ++q) { int i = base + q; if (i < n) s += in[i]; }
#pragma unroll
  for (int off = 32; off > 0; off >>= 1) s += __shfl_down(s, off);
  __shared__ int ws[4];
  int w = t >> 6, lane = t & 63;
  if (lane == 0) ws[w] = s;
  __syncthreads();
  if (t == 0) bsum[blk] = ws[0] + ws[1] + ws[2] + ws[3];
}

// ---- phase 2: block-local exscan + base from <=64 block sums; writes out[n] too ----
__global__ void k_scanout(const int* __restrict__ in, int n,
                          const int* __restrict__ bsum, int* __restrict__ out) {
  int blk = blockIdx.x, t = threadIdx.x;
  int w = t >> 6, lane = t & 63;
  __shared__ int sbase;
  __shared__ int wtot[4];
  if (w == 0) {                       // block base = sum of bsum[0..blk)  (grid <= 64)
    int v = (lane < blk) ? bsum[lane] : 0;
#pragma unroll
    for (int off = 32; off > 0; off >>= 1) v += __shfl_down(v, off);
    if (lane == 0) sbase = v;
  }
  int base = blk * 1024 + t * 4;
  int a0 = (base < n) ? in[base] : 0;
  int a1 = (base + 1 < n) ? in[base + 1] : 0;
  int a2 = (base + 2 < n) ? in[base + 2] : 0;
  int a3 = (base + 3 < n) ? in[base + 3] : 0;
  int s = a0 + a1 + a2 + a3;
  int inc = s;
#pragma unroll
  for (int off = 1; off < 64; off <<= 1) {
    int vv = __shfl_up(inc, off);
    if (lane >= off) inc += vv;
  }
  if (lane == 63) wtot[w] = inc;
  __syncthreads();
  int wbase = 0;
  for (int q = 0; q < w; ++q) wbase += wtot[q];
  int ex = sbase + wbase + inc - s;   // exclusive prefix for this thread's first elem
  if (base < n) out[base] = ex; ex += a0;
  if (base + 1 < n) out[base + 1] = ex; ex += a1;
  if (base + 2 < n) out[base + 2] = ex; ex += a2;
  if (base + 3 < n) out[base + 3] = ex; ex += a3;
  if (blk == (int)gridDim.x - 1 && t == 255) out[n] = ex;   // grand total
}

// ---- fill dst-CSR ----
__global__ void k_fillcsr(const int* __restrict__ dst, const int* __restrict__ rowptr,
                          int* __restrict__ cursor, int* __restrict__ col) {
  int e = blockIdx.x * 256 + threadIdx.x;
  int v = dst[e];
  int p = atomicAdd(&cursor[v], 1);
  col[rowptr[v] + p] = e;
}

// ---- neighbor aggregation + info + attn + x_score (fp32, 4-way gather ILP) ----
__global__ void k_agg(const float* __restrict__ feat, const float* __restrict__ e_feat,
                      const int* __restrict__ src, const int* __restrict__ col,
                      const int* __restrict__ rowptr, const int* __restrict__ outd,
                      const int* __restrict__ ind, const float* __restrict__ waf,
                      float* __restrict__ out_xs) {
  __shared__ int su[4][CAP_];
  __shared__ float ssc[4][CAP_];
  int w = threadIdx.x >> 6, lane = threadIdx.x & 63;
  int v = blockIdx.x * 4 + w;
  int r0 = rowptr[v], r1 = rowptr[v + 1];
  int m = r1 - r0;
  int mm = m < CAP_ ? m : CAP_;
  for (int s = lane; s < mm; s += 64) {
    int e = col[r0 + s];
    int u = src[e];
    float sc = (u == v) ? 0.f : e_feat[e] / sqrtf(fmaxf((float)outd[u], 1.f));
    su[w][s] = u;
    ssc[w][s] = sc;
  }
  __syncthreads();
  const float2* f2 = (const float2*)feat;
  float2 f = f2[(size_t)v * 64 + lane];
  float ax = 0.f, ay = 0.f;
  int s = 0;
  for (; s + 4 <= mm; s += 4) {       // 4 independent 512B gathers in flight
    int u0 = su[w][s], u1 = su[w][s + 1], u2 = su[w][s + 2], u3 = su[w][s + 3];
    float c0 = ssc[w][s], c1 = ssc[w][s + 1], c2 = ssc[w][s + 2], c3 = ssc[w][s + 3];
    float2 f0 = f2[(size_t)u0 * 64 + lane];
    float2 f1 = f2[(size_t)u1 * 64 + lane];
    float2 fq = f2[(size_t)u2 * 64 + lane];
    float2 f3 = f2[(size_t)u3 * 64 + lane];
    ax += f0.x * c0 + f1.x * c1 + fq.x * c2 + f3.x * c3;
    ay += f0.y * c0 + f1.y * c1 + fq.y * c2 + f3.y * c3;
  }
  for (; s < mm; ++s) {
    float2 fu = f2[(size_t)su[w][s] * 64 + lane];
    ax += fu.x * ssc[w][s];
    ay += fu.y * ssc[w][s];
  }
  for (int sP = r0 + CAP_; sP < r1; ++sP) {     // statistically never taken
    int e = col[sP];
    int u = src[e];
    if (u == v) continue;
    float sc = e_feat[e] / sqrtf(fmaxf((float)outd[u], 1.f));
    float2 fu = f2[(size_t)u * 64 + lane];
    ax += fu.x * sc;
    ay += fu.y * sc;
  }
  float dn = 1.f / sqrtf(fmaxf((float)ind[v], 1.f));
  float info = fabsf(f.x - ax * dn) + fabsf(f.y - ay * dn);
  float dot = f.x * waf[2 * lane] + f.y * waf[2 * lane + 1];
#pragma unroll
  for (int off = 32; off > 0; off >>= 1) {
    info += __shfl_down(info, off);
    dot  += __shfl_down(dot, off);
  }
  if (lane == 0) {
    float sA = dot >= 0.f ? dot : 0.2f * dot;   // leaky_relu 0.2
    float attn = 1.f / (1.f + expf(-sA));
    out_xs[v] = info * attn;
  }
}

// ---- per-graph top-K: bitonic sort of u64-packed (f32 value desc, idx asc) ----
// x >= 0 so IEEE bits order == numeric order. key = (bits<<32) | (N-1-idx).
__global__ void k_topk(const float* __restrict__ xs, float* __restrict__ out_perm,
                       int* __restrict__ perm_i, int* __restrict__ maskarr) {
  __shared__ unsigned long long dv[1024];
  int b = blockIdx.x, t = threadIdx.x;
  for (int i = t; i < 1024; i += 256) {
    unsigned bits = __float_as_uint(xs[b * 1024 + i]);
    dv[i] = ((unsigned long long)bits << 32) | (unsigned)(N_ - 1 - i);
  }
  __syncthreads();
  for (int k2 = 2; k2 <= 1024; k2 <<= 1) {
    for (int j = k2 >> 1; j > 0; j >>= 1) {
      for (int i = t; i < 1024; i += 256) {
        int ixj = i ^ j;
        if (ixj > i) {
          unsigned long long a = dv[i], c = dv[ixj];
          bool dir = ((i & k2) == 0);              // true -> descending segment
          if ((a > c) != dir) { dv[i] = c; dv[ixj] = a; }
        }
      }
      __syncthreads();
    }
  }
  for (int r = t; r < K_; r += 256) {
    int idx = N_ - 1 - (int)(dv[r] & 0xFFFFFFFFull);
    int node = b * N_ + idx;
    int pos = b * K_ + r;
    out_perm[pos] = (float)node;    // output buffer is float32 view
    perm_i[pos] = node;
    maskarr[node] = pos;
  }
}

// ---- gather feat_p + wsrc/wdst dots (one wave per pooled row, fp32) ----
__global__ void k_gather(const float* __restrict__ feat, const int* __restrict__ perm_i,
                         const float* __restrict__ att, float* __restrict__ out_featp,
                         float* __restrict__ wsrc, float* __restrict__ wdst) {
  int gid = blockIdx.x * 256 + threadIdx.x;
  int p = gid >> 6, lane = gid & 63;
  int node = perm_i[p];
  float2 f = ((const float2*)feat)[(size_t)node * 64 + lane];
  ((float2*)out_featp)[(size_t)p * 64 + lane] = f;
  float s1 = f.x * att[2 * lane] + f.y * att[2 * lane + 1];
  float s2 = f.x * att[D_ + 2 * lane] + f.y * att[D_ + 2 * lane + 1];
#pragma unroll
  for (int off = 32; off > 0; off >>= 1) {
    s1 += __shfl_down(s1, off);
    s2 += __shfl_down(s2, off);
  }
  if (lane == 0) { wsrc[p] = s1; wdst[p] = s2; }
}

// ---- pooled-subgraph edge CSR keyed by pooled dst column ----
__global__ void k_cnt2(const int* __restrict__ src, const int* __restrict__ dst,
                       const int* __restrict__ maskarr, int* __restrict__ cnt2) {
  int e = blockIdx.x * 256 + threadIdx.x;
  int nr = maskarr[src[e]], nc = maskarr[dst[e]];
  if (nr >= 0 && nc >= 0) atomicAdd(&cnt2[nc], 1);
}

__global__ void k_fill2(const int* __restrict__ src, const int* __restrict__ dst,
                        const int* __restrict__ maskarr, const float* __restrict__ e_feat,
                        const int* __restrict__ rowptr2, int* __restrict__ cursor2,
                        int* __restrict__ colii, float* __restrict__ colval) {
  int e = blockIdx.x * 256 + threadIdx.x;
  int nr = maskarr[src[e]], nc = maskarr[dst[e]];
  if (nr >= 0 && nc >= 0) {
    int p = atomicAdd(&cursor2[nc], 1);
    int s = rowptr2[nc] + p;
    colii[s] = nr;                 // global pooled src index (b*K + i)
    colval[s] = 1.0f * e_feat[e];  // LAMB = 1
  }
}

// ---- dedupe duplicate (i,j) edges per column + pre-gather (wsrc[ii], E) pairs ----
__global__ void k_dedupe(const int* __restrict__ rowptr2, int* __restrict__ colii,
                         float* __restrict__ colval, int* __restrict__ ucnt,
                         const float* __restrict__ wsrc, float2* __restrict__ bval) {
  int c = blockIdx.x * 256 + threadIdx.x;
  int r0 = rowptr2[c], r1 = rowptr2[c + 1];
  int w = r0;
  for (int s = r0; s < r1; ++s) {
    int ii = colii[s];
    if (ii < 0) continue;
    float E = colval[s];
    for (int t2 = s + 1; t2 < r1; ++t2)
      if (colii[t2] == ii) { E += colval[t2]; colii[t2] = -1; }
    colii[w] = ii; colval[w] = E; ++w;
  }
  ucnt[c] = w - r0;
  for (int s = r0; s < w; ++s) bval[s] = make_float2(wsrc[colii[s]], colval[s]);
}

// ---- per-graph sort of wsrc (desc) + prefix sums ----
__global__ void k_gsort(const float* __restrict__ wsrc, float* __restrict__ ws_sorted,
                        float* __restrict__ psum) {
  __shared__ float sv[1024];
  __shared__ float sc[1024];
  int b = blockIdx.x, t = threadIdx.x;
  for (int i = t; i < 1024; i += 256) sv[i] = (i < K_) ? wsrc[b * K_ + i] : -INFINITY;
  __syncthreads();
  for (int k2 = 2; k2 <= 1024; k2 <<= 1) {
    for (int j = k2 >> 1; j > 0; j >>= 1) {
      for (int i = t; i < 1024; i += 256) {
        int ixj = i ^ j;
        if (ixj > i) {
          float a = sv[i], c = sv[ixj];
          bool dir = ((i & k2) == 0);
          bool swapv = dir ? (c > a) : (a > c);
          if (swapv) { sv[i] = c; sv[ixj] = a; }
        }
      }
      __syncthreads();
    }
  }
  for (int i = t; i < 1024; i += 256) { ws_sorted[b * 1024 + i] = sv[i]; sc[i] = sv[i]; }
  __syncthreads();
  for (int off = 1; off < 1024; off <<= 1) {
    float tmp[4];
    for (int i = t, q = 0; i < 1024; i += 256, ++q) tmp[q] = (i >= off) ? sc[i - off] : 0.f;
    __syncthreads();
    for (int i = t, q = 0; i < 1024; i += 256, ++q) sc[i] += tmp[q];
    __syncthreads();
  }
  if (t == 0) psum[b * 1025] = 0.f;
  for (int i = t; i < 1024; i += 256) psum[b * 1025 + 1 + i] = sc[i];
}

// count of entries > thr in desc-sorted LDS array, searching index range [lo,hi)
__device__ __forceinline__ int cnt_gt_rng(const float* __restrict__ arr, float thr,
                                          int lo, int hi) {
  while (lo < hi) {
    int mid = (lo + hi) >> 1;
    if (arr[mid] > thr) lo = mid + 1; else hi = mid;
  }
  return lo;
}

// ---- tau per column via bisection on g(t) = sum max(z-t,0) = 1 ----
__global__ void __launch_bounds__(128) k_tau(
    const float* __restrict__ wdst,
    const float* __restrict__ ws_sorted, const float* __restrict__ psum,
    const int* __restrict__ rowptr2, const int* __restrict__ ucnt,
    const float2* __restrict__ bval, float* __restrict__ tauv) {
  __shared__ float swss[1024];
  __shared__ float sps[1025];
  int b = blockIdx.x / CPB_;
  int chunk = blockIdx.x % CPB_;
  int t0 = threadIdx.x;
  for (int i = t0; i < 1024; i += 128) swss[i] = ws_sorted[b * 1024 + i];
  for (int i = t0; i < 1025; i += 128) sps[i] = psum[b * 1025 + i];
  __syncthreads();

  int j = chunk * CH_ + t0;
  if (j >= K_) return;
  int c = b * K_ + j;

  float wd = wdst[c];
  int p = cnt_gt_rng(swss, -wd, 0, K_);
  float psp = sps[p];
  int r0 = rowptr2[c], m = ucnt[c];

  float mz = lrelu(swss[0] + wd);
  for (int s = 0; s < m; ++s) {
    float2 v = bval[r0 + s];
    mz = fmaxf(mz, lrelu(v.x + wd) + v.y);       // E > 0 (e_feat=1, LAMB=1)
  }

  float lo = mz - 1.0f, hi = mz;                 // g(mz)=0<1, g(mz-1)>=1
  int nmin = 0, nmax = K_;                       // support-count bracket
  for (int it = 0; it < 22; ++it) {
    float t = 0.5f * (lo + hi);
    float wthr = (t >= 0.f ? t : 5.f * t) - wd;
    int n = cnt_gt_rng(swss, wthr, nmin, nmax);
    float bsum = (n <= p) ? (sps[n] + n * wd)
                          : (psp + p * wd + NEG_ * (sps[n] - psp + (n - p) * wd));
    float g = bsum - n * t;
    for (int s = 0; s < m; ++s) {
      float2 v = bval[r0 + s];
      float bse = lrelu(v.x + wd);
      g += fmaxf(bse + v.y - t, 0.f) - fmaxf(bse - t, 0.f);
    }
    if (g > 1.f) { lo = t; nmax = n; } else { hi = t; nmin = n; }
  }
  float t = lo;                                  // t <= tau*, bracket ~2.4e-7
  float wthr = (t >= 0.f ? t : 5.f * t) - wd;
  int n = cnt_gt_rng(swss, wthr, nmin, nmax);
  float S = (n <= p) ? (sps[n] + n * wd)
                     : (psp + p * wd + NEG_ * (sps[n] - psp + (n - p) * wd));
  int cc = n;
  for (int s = 0; s < m; ++s) {
    float2 v = bval[r0 + s];
    float bse = lrelu(v.x + wd);
    float zz = bse + v.y;
    if (v.x > wthr) { S -= bse; cc -= 1; }       // same predicate as cnt -> exact cancel
    if (zz > t)     { S += zz;  cc += 1; }
  }
  float tau = (cc < 1) ? (mz - 1.0f) : ((S - 1.0f) / (float)cc);
  tau = fminf(fmaxf(tau, mz - 1.0f), mz);        // true tau* in [mz-1, mz)
  tauv[c] = tau;
}

// ---- dense weights: float4 per thread (820 = 205*4), coalesced dwordx4 ----
__global__ void k_dense(const float* __restrict__ wsrc, const float* __restrict__ wdst,
                        const float* __restrict__ tauv, float* __restrict__ out_w) {
  int t = threadIdx.x;
  int j4 = t * 4;
  if (j4 >= K_) return;
  int row = blockIdx.x;                         // b*K + i
  int b = row / K_;
  const float4* wd4 = (const float4*)(wdst + b * K_);
  const float4* ta4 = (const float4*)(tauv + b * K_);
  float ws = wsrc[row];
  float4 wd = wd4[t];
  float4 ta = ta4[t];
  float4 o;
  float z;
  z = lrelu(ws + wd.x) - ta.x; o.x = (z > 1e-9f) ? z : 0.f;
  z = lrelu(ws + wd.y) - ta.y; o.y = (z > 1e-9f) ? z : 0.f;
  z = lrelu(ws + wd.z) - ta.z; o.z = (z > 1e-9f) ? z : 0.f;
  z = lrelu(ws + wd.w) - ta.w; o.w = (z > 1e-9f) ? z : 0.f;
  ((float4*)(out_w + (size_t)row * K_))[t] = o;
}

// ---- rewrite the edge-perturbed entries with the correct value ----
__global__ void k_fix(const float* __restrict__ wsrc, const float* __restrict__ wdst,
                      const float* __restrict__ tauv, const int* __restrict__ rowptr2,
                      const int* __restrict__ ucnt, const int* __restrict__ colii,
                      const float* __restrict__ colval, float* __restrict__ out_w) {
  int c = blockIdx.x * 256 + threadIdx.x;
  int b = c / K_;
  int j = c - b * K_;
  float wd = wdst[c], ta = tauv[c];
  int r0 = rowptr2[c], m = ucnt[c];
  for (int s = 0; s < m; ++s) {
    int nr = colii[r0 + s];
    float z = lrelu(wsrc[nr] + wd) + colval[r0 + s];
    float v = z - ta;
    out_w[(size_t)nr * K_ + j] = (v > 1e-9f) ? v : 0.f;
  }
}

extern "C" void kernel_launch(void* const* d_in, const int* in_sizes, int n_in,
                              void* d_out, int out_size, void* d_ws, size_t ws_size,
                              hipStream_t stream) {
  const float* feat   = (const float*)d_in[0];
  const float* e_feat = (const float*)d_in[1];
  const float* W      = (const float*)d_in[2];
  const float* a      = (const float*)d_in[3];
  const float* att    = (const float*)d_in[4];
  const int*   src    = (const int*)d_in[5];
  const int*   dst    = (const int*)d_in[6];

  float* out_featp = (float*)d_out;                       // [BK*D]
  float* out_w     = out_featp + (size_t)BK_ * D_;        // [BK*K]
  float* out_perm  = out_w + (size_t)BK_ * K_;            // [BK]
  float* out_xs    = out_perm + BK_;                      // [NTOT]

  char* wsp = (char*)d_ws;
  auto carve = [&](size_t bytes) -> void* {
    void* pp = (void*)wsp;
    wsp += (bytes + 255) & ~(size_t)255;
    return pp;
  };
  float* waf       = (float*)carve((size_t)D_ * 4);
  float* wsrc      = (float*)carve((size_t)BK_ * 4);
  float* wdst      = (float*)carve((size_t)BK_ * 4);
  float* tauv      = (float*)carve((size_t)BK_ * 4);
  float* colval    = (float*)carve((size_t)ETOT_ * 4);
  float2* bval     = (float2*)carve((size_t)ETOT_ * 8);
  float* ws_sorted = (float*)carve((size_t)B_ * 1024 * 4);
  float* psum      = (float*)carve((size_t)B_ * 1025 * 4);
  int* rowptr      = (int*)carve((size_t)(NTOT_ + 1) * 4);
  int* rowptr2     = (int*)carve((size_t)(BK_ + 1) * 4);
  int* col         = (int*)carve((size_t)ETOT_ * 4);
  int* colii       = (int*)carve((size_t)ETOT_ * 4);
  int* perm_i      = (int*)carve((size_t)BK_ * 4);
  int* bsumA       = (int*)carve(64 * 4);
  int* bsumB       = (int*)carve(64 * 4);
  size_t zbytes    = ((size_t)NTOT_ * 3 + (size_t)BK_ * 2) * 4;
  int* zblk        = (int*)carve(zbytes);
  int* in_deg      = zblk;
  int* out_deg     = zblk + NTOT_;
  int* cursor      = zblk + 2 * NTOT_;
  int* cnt2        = zblk + 3 * NTOT_;
  int* cursor2     = cnt2 + BK_;
  int* maskarr     = (int*)carve((size_t)NTOT_ * 4);

  hipMemsetAsync(zblk, 0, zbytes, stream);
  hipMemsetAsync(maskarr, 0xFF, (size_t)NTOT_ * 4, stream);   // -1

  const int nbA = (NTOT_ + 1023) / 1024;   // 64
  const int nbB = (BK_ + 1023) / 1024;     // 52

  k_wa<<<1, 128, 0, stream>>>(W, a, waf);
  k_deg<<<ETOT_ / 256, 256, 0, stream>>>(src, dst, out_deg, in_deg);
  k_scansum<<<nbA, 256, 0, stream>>>(in_deg, NTOT_, bsumA);
  k_scanout<<<nbA, 256, 0, stream>>>(in_deg, NTOT_, bsumA, rowptr);
  k_fillcsr<<<ETOT_ / 256, 256, 0, stream>>>(dst, rowptr, cursor, col);
  k_agg<<<NTOT_ / 4, 256, 0, stream>>>(feat, e_feat, src, col, rowptr, out_deg, in_deg,
                                       waf, out_xs);
  k_topk<<<B_, 256, 0, stream>>>(out_xs, out_perm, perm_i, maskarr);
  k_gather<<<BK_ / 4, 256, 0, stream>>>(feat, perm_i, att, out_featp, wsrc, wdst);
  k_cnt2<<<ETOT_ / 256, 256, 0, stream>>>(src, dst, maskarr, cnt2);
  k_scansum<<<nbB, 256, 0, stream>>>(cnt2, BK_, bsumB);
  k_scanout<<<nbB, 256, 0, stream>>>(cnt2, BK_, bsumB, rowptr2);
  k_fill2<<<ETOT_ / 256, 256, 0, stream>>>(src, dst, maskarr, e_feat, rowptr2, cursor2,
                                           colii, colval);
  k_dedupe<<<BK_ / 256, 256, 0, stream>>>(rowptr2, colii, colval, cursor2, wsrc, bval);
  k_gsort<<<B_, 256, 0, stream>>>(wsrc, ws_sorted, psum);
  k_tau<<<B_ * CPB_, 128, 0, stream>>>(wdst, ws_sorted, psum, rowptr2, cursor2,
                                       bval, tauv);
  k_dense<<<BK_, 256, 0, stream>>>(wsrc, wdst, tauv, out_w);
  k_fix<<<BK_ / 256, 256, 0, stream>>>(wsrc, wdst, tauv, rowptr2, cursor2, colii, colval,
                                       out_w);
}

// Round 7
// 539.472 us; speedup vs baseline: 1.7473x; 1.0570x over previous
//
#include <hip/hip_runtime.h>
#include <math.h>

// HGPSLPool: B=64 graphs, N=1024 nodes, D=128, EPG=8192, K=820.
// Outputs (concat, float32 view): feat_p [B*K*D], weights [B*K*K], perm [B*K], x_score [NTOT].

static constexpr int B_    = 64;
static constexpr int N_    = 1024;
static constexpr int D_    = 128;
static constexpr int NTOT_ = B_ * N_;     // 65536
static constexpr int ETOT_ = B_ * 8192;   // 524288
static constexpr int K_    = 820;
static constexpr int BK_   = B_ * K_;     // 52480
static constexpr float NEG_ = 0.2f;
static constexpr int CH_   = 128;         // k_tau: columns per block
static constexpr int CPB_  = 7;           // chunks per graph (7*128=896 >= 820)
static constexpr int CAP_  = 64;          // k_agg: staged edges per node (max in-deg ~30)

__device__ __forceinline__ float lrelu(float x) { return x >= 0.f ? x : NEG_ * x; }

// ---- wa = W @ a (fp64 accumulate, fp32 out), 1 block x 128 ----
__global__ void k_wa(const float* __restrict__ W, const float* __restrict__ a,
                     float* __restrict__ waf) {
  int d = threadIdx.x;
  double s = 0.0;
  for (int k = 0; k < D_; ++k) s += (double)W[d * D_ + k] * (double)a[k];
  waf[d] = (float)s;
}

// ---- degrees (self-loops included, matching ref) ----
__global__ void k_deg(const int* __restrict__ src, const int* __restrict__ dst,
                      int* __restrict__ outd, int* __restrict__ ind) {
  int e = blockIdx.x * 256 + threadIdx.x;
  atomicAdd(&outd[src[e]], 1);
  atomicAdd(&ind[dst[e]], 1);
}

// ---- parallel exclusive scan, phase 1: per-block (1024-elem chunk) sums ----
__global__ void k_scansum(const int* __restrict__ in, int n, int* __restrict__ bsum) {
  int blk = blockIdx.x, t = threadIdx.x;
  int base = blk * 1024 + t * 4;
  int s = 0;
#pragma unroll
  for (int q = 0; q < 4; ++q) { int i = base + q; if (i < n) s += in[i]; }
#pragma unroll
  for (int off = 32; off > 0; off >>= 1) s += __shfl_down(s, off);
  __shared__ int ws[4];
  int w = t >> 6, lane = t & 63;
  if (lane == 0) ws[w] = s;
  __syncthreads();
  if (t == 0) bsum[blk] = ws[0] + ws[1] + ws[2] + ws[3];
}

// ---- phase 2: block-local exscan + base from <=64 block sums; writes out[n] too ----
__global__ void k_scanout(const int* __restrict__ in, int n,
                          const int* __restrict__ bsum, int* __restrict__ out) {
  int blk = blockIdx.x, t = threadIdx.x;
  int w = t >> 6, lane = t & 63;
  __shared__ int sbase;
  __shared__ int wtot[4];
  if (w == 0) {                       // block base = sum of bsum[0..blk)  (grid <= 64)
    int v = (lane < blk) ? bsum[lane] : 0;
#pragma unroll
    for (int off = 32; off > 0; off >>= 1) v += __shfl_down(v, off);
    if (lane == 0) sbase = v;
  }
  int base = blk * 1024 + t * 4;
  int a0 = (base < n) ? in[base] : 0;
  int a1 = (base + 1 < n) ? in[base + 1] : 0;
  int a2 = (base + 2 < n) ? in[base + 2] : 0;
  int a3 = (base + 3 < n) ? in[base + 3] : 0;
  int s = a0 + a1 + a2 + a3;
  int inc = s;
#pragma unroll
  for (int off = 1; off < 64; off <<= 1) {
    int vv = __shfl_up(inc, off);
    if (lane >= off) inc += vv;
  }
  if (lane == 63) wtot[w] = inc;
  __syncthreads();
  int wbase = 0;
  for (int q = 0; q < w; ++q) wbase += wtot[q];
  int ex = sbase + wbase + inc - s;   // exclusive prefix for this thread's first elem
  if (base < n) out[base] = ex; ex += a0;
  if (base + 1 < n) out[base + 1] = ex; ex += a1;
  if (base + 2 < n) out[base + 2] = ex; ex += a2;
  if (base + 3 < n) out[base + 3] = ex; ex += a3;
  if (blk == (int)gridDim.x - 1 && t == 255) out[n] = ex;   // grand total
}

// ---- fill dst-CSR ----
__global__ void k_fillcsr(const int* __restrict__ dst, const int* __restrict__ rowptr,
                          int* __restrict__ cursor, int* __restrict__ col) {
  int e = blockIdx.x * 256 + threadIdx.x;
  int v = dst[e];
  int p = atomicAdd(&cursor[v], 1);
  col[rowptr[v] + p] = e;
}

// ---- neighbor aggregation + info + attn + x_score (fp32, 4-way gather ILP) ----
// XCD-aware swizzle: with round-robin block->XCD dispatch, vb=(g&7)*2048+(g>>3)
// gives XCD x exactly graphs [8x,8x+8) -> per-XCD feat working set = 4MB = L2.
__global__ void k_agg(const float* __restrict__ feat, const float* __restrict__ e_feat,
                      const int* __restrict__ src, const int* __restrict__ col,
                      const int* __restrict__ rowptr, const int* __restrict__ outd,
                      const int* __restrict__ ind, const float* __restrict__ waf,
                      float* __restrict__ out_xs) {
  __shared__ int su[4][CAP_];
  __shared__ float ssc[4][CAP_];
  int g = blockIdx.x;
  int vb = (g & 7) * 2048 + (g >> 3);           // 16384 blocks / 8 XCDs
  int w = threadIdx.x >> 6, lane = threadIdx.x & 63;
  int v = vb * 4 + w;
  int r0 = rowptr[v], r1 = rowptr[v + 1];
  int m = r1 - r0;
  int mm = m < CAP_ ? m : CAP_;
  for (int s = lane; s < mm; s += 64) {
    int e = col[r0 + s];
    int u = src[e];
    float sc = (u == v) ? 0.f : e_feat[e] / sqrtf(fmaxf((float)outd[u], 1.f));
    su[w][s] = u;
    ssc[w][s] = sc;
  }
  __syncthreads();
  const float2* f2 = (const float2*)feat;
  float2 f = f2[(size_t)v * 64 + lane];
  float ax = 0.f, ay = 0.f;
  int s = 0;
  for (; s + 4 <= mm; s += 4) {       // 4 independent 512B gathers in flight
    int u0 = su[w][s], u1 = su[w][s + 1], u2 = su[w][s + 2], u3 = su[w][s + 3];
    float c0 = ssc[w][s], c1 = ssc[w][s + 1], c2 = ssc[w][s + 2], c3 = ssc[w][s + 3];
    float2 f0 = f2[(size_t)u0 * 64 + lane];
    float2 f1 = f2[(size_t)u1 * 64 + lane];
    float2 fq = f2[(size_t)u2 * 64 + lane];
    float2 f3 = f2[(size_t)u3 * 64 + lane];
    ax += f0.x * c0 + f1.x * c1 + fq.x * c2 + f3.x * c3;
    ay += f0.y * c0 + f1.y * c1 + fq.y * c2 + f3.y * c3;
  }
  for (; s < mm; ++s) {
    float2 fu = f2[(size_t)su[w][s] * 64 + lane];
    ax += fu.x * ssc[w][s];
    ay += fu.y * ssc[w][s];
  }
  for (int sP = r0 + CAP_; sP < r1; ++sP) {     // statistically never taken
    int e = col[sP];
    int u = src[e];
    if (u == v) continue;
    float sc = e_feat[e] / sqrtf(fmaxf((float)outd[u], 1.f));
    float2 fu = f2[(size_t)u * 64 + lane];
    ax += fu.x * sc;
    ay += fu.y * sc;
  }
  float dn = 1.f / sqrtf(fmaxf((float)ind[v], 1.f));
  float info = fabsf(f.x - ax * dn) + fabsf(f.y - ay * dn);
  float dot = f.x * waf[2 * lane] + f.y * waf[2 * lane + 1];
#pragma unroll
  for (int off = 32; off > 0; off >>= 1) {
    info += __shfl_down(info, off);
    dot  += __shfl_down(dot, off);
  }
  if (lane == 0) {
    float sA = dot >= 0.f ? dot : 0.2f * dot;   // leaky_relu 0.2
    float attn = 1.f / (1.f + expf(-sA));
    out_xs[v] = info * attn;
  }
}

// ---- per-graph top-K: bitonic sort of u64-packed (f32 value desc, idx asc) ----
// x >= 0 so IEEE bits order == numeric order. key = (bits<<32) | (N-1-idx).
__global__ void k_topk(const float* __restrict__ xs, float* __restrict__ out_perm,
                       int* __restrict__ perm_i, int* __restrict__ maskarr) {
  __shared__ unsigned long long dv[1024];
  int b = blockIdx.x, t = threadIdx.x;
  for (int i = t; i < 1024; i += 512) {
    unsigned bits = __float_as_uint(xs[b * 1024 + i]);
    dv[i] = ((unsigned long long)bits << 32) | (unsigned)(N_ - 1 - i);
  }
  __syncthreads();
  for (int k2 = 2; k2 <= 1024; k2 <<= 1) {
    for (int j = k2 >> 1; j > 0; j >>= 1) {
      for (int i = t; i < 1024; i += 512) {
        int ixj = i ^ j;
        if (ixj > i) {
          unsigned long long a = dv[i], c = dv[ixj];
          bool dir = ((i & k2) == 0);              // true -> descending segment
          if ((a > c) != dir) { dv[i] = c; dv[ixj] = a; }
        }
      }
      __syncthreads();
    }
  }
  for (int r = t; r < K_; r += 512) {
    int idx = N_ - 1 - (int)(dv[r] & 0xFFFFFFFFull);
    int node = b * N_ + idx;
    int pos = b * K_ + r;
    out_perm[pos] = (float)node;    // output buffer is float32 view
    perm_i[pos] = node;
    maskarr[node] = pos;
  }
}

// ---- gather feat_p + wsrc/wdst dots (one wave per pooled row, fp32) ----
// Same XCD swizzle: 13120 blocks, graph spans 205 blocks -> XCD x gets graphs [8x,8x+8).
__global__ void k_gather(const float* __restrict__ feat, const int* __restrict__ perm_i,
                         const float* __restrict__ att, float* __restrict__ out_featp,
                         float* __restrict__ wsrc, float* __restrict__ wdst) {
  int g = blockIdx.x;
  int vb = (g & 7) * 1640 + (g >> 3);           // 13120 / 8
  int gid = vb * 256 + threadIdx.x;
  int p = gid >> 6, lane = gid & 63;
  int node = perm_i[p];
  float2 f = ((const float2*)feat)[(size_t)node * 64 + lane];
  ((float2*)out_featp)[(size_t)p * 64 + lane] = f;
  float s1 = f.x * att[2 * lane] + f.y * att[2 * lane + 1];
  float s2 = f.x * att[D_ + 2 * lane] + f.y * att[D_ + 2 * lane + 1];
#pragma unroll
  for (int off = 32; off > 0; off >>= 1) {
    s1 += __shfl_down(s1, off);
    s2 += __shfl_down(s2, off);
  }
  if (lane == 0) { wsrc[p] = s1; wdst[p] = s2; }
}

// ---- pooled-subgraph edge CSR keyed by pooled dst column ----
__global__ void k_cnt2(const int* __restrict__ src, const int* __restrict__ dst,
                       const int* __restrict__ maskarr, int* __restrict__ cnt2) {
  int e = blockIdx.x * 256 + threadIdx.x;
  int nr = maskarr[src[e]], nc = maskarr[dst[e]];
  if (nr >= 0 && nc >= 0) atomicAdd(&cnt2[nc], 1);
}

__global__ void k_fill2(const int* __restrict__ src, const int* __restrict__ dst,
                        const int* __restrict__ maskarr, const float* __restrict__ e_feat,
                        const int* __restrict__ rowptr2, int* __restrict__ cursor2,
                        int* __restrict__ colii, float* __restrict__ colval) {
  int e = blockIdx.x * 256 + threadIdx.x;
  int nr = maskarr[src[e]], nc = maskarr[dst[e]];
  if (nr >= 0 && nc >= 0) {
    int p = atomicAdd(&cursor2[nc], 1);
    int s = rowptr2[nc] + p;
    colii[s] = nr;                 // global pooled src index (b*K + i)
    colval[s] = 1.0f * e_feat[e];  // LAMB = 1
  }
}

// ---- dedupe duplicate (i,j) edges per column + pre-gather (wsrc[ii], E) pairs ----
__global__ void k_dedupe(const int* __restrict__ rowptr2, int* __restrict__ colii,
                         float* __restrict__ colval, int* __restrict__ ucnt,
                         const float* __restrict__ wsrc, float2* __restrict__ bval) {
  int c = blockIdx.x * 256 + threadIdx.x;
  int r0 = rowptr2[c], r1 = rowptr2[c + 1];
  int w = r0;
  for (int s = r0; s < r1; ++s) {
    int ii = colii[s];
    if (ii < 0) continue;
    float E = colval[s];
    for (int t2 = s + 1; t2 < r1; ++t2)
      if (colii[t2] == ii) { E += colval[t2]; colii[t2] = -1; }
    colii[w] = ii; colval[w] = E; ++w;
  }
  ucnt[c] = w - r0;
  for (int s = r0; s < w; ++s) bval[s] = make_float2(wsrc[colii[s]], colval[s]);
}

// ---- per-graph sort of wsrc (desc) + prefix sums (512 threads) ----
__global__ void k_gsort(const float* __restrict__ wsrc, float* __restrict__ ws_sorted,
                        float* __restrict__ psum) {
  __shared__ float sv[1024];
  __shared__ float sc[1024];
  int b = blockIdx.x, t = threadIdx.x;
  for (int i = t; i < 1024; i += 512) sv[i] = (i < K_) ? wsrc[b * K_ + i] : -INFINITY;
  __syncthreads();
  for (int k2 = 2; k2 <= 1024; k2 <<= 1) {
    for (int j = k2 >> 1; j > 0; j >>= 1) {
      for (int i = t; i < 1024; i += 512) {
        int ixj = i ^ j;
        if (ixj > i) {
          float a = sv[i], c = sv[ixj];
          bool dir = ((i & k2) == 0);
          bool swapv = dir ? (c > a) : (a > c);
          if (swapv) { sv[i] = c; sv[ixj] = a; }
        }
      }
      __syncthreads();
    }
  }
  for (int i = t; i < 1024; i += 512) { ws_sorted[b * 1024 + i] = sv[i]; sc[i] = sv[i]; }
  __syncthreads();
  for (int off = 1; off < 1024; off <<= 1) {
    float tmp[2];
    for (int i = t, q = 0; i < 1024; i += 512, ++q) tmp[q] = (i >= off) ? sc[i - off] : 0.f;
    __syncthreads();
    for (int i = t, q = 0; i < 1024; i += 512, ++q) sc[i] += tmp[q];
    __syncthreads();
  }
  if (t == 0) psum[b * 1025] = 0.f;
  for (int i = t; i < 1024; i += 512) psum[b * 1025 + 1 + i] = sc[i];
}

// count of entries > thr in desc-sorted LDS array, searching index range [lo,hi)
__device__ __forceinline__ int cnt_gt_rng(const float* __restrict__ arr, float thr,
                                          int lo, int hi) {
  while (lo < hi) {
    int mid = (lo + hi) >> 1;
    if (arr[mid] > thr) lo = mid + 1; else hi = mid;
  }
  return lo;
}

// ---- tau per column via bisection on g(t) = sum max(z-t,0) = 1 ----
__global__ void __launch_bounds__(128) k_tau(
    const float* __restrict__ wdst,
    const float* __restrict__ ws_sorted, const float* __restrict__ psum,
    const int* __restrict__ rowptr2, const int* __restrict__ ucnt,
    const float2* __restrict__ bval, float* __restrict__ tauv) {
  __shared__ float swss[1024];
  __shared__ float sps[1025];
  int b = blockIdx.x / CPB_;
  int chunk = blockIdx.x % CPB_;
  int t0 = threadIdx.x;
  for (int i = t0; i < 1024; i += 128) swss[i] = ws_sorted[b * 1024 + i];
  for (int i = t0; i < 1025; i += 128) sps[i] = psum[b * 1025 + i];
  __syncthreads();

  int j = chunk * CH_ + t0;
  if (j >= K_) return;
  int c = b * K_ + j;

  float wd = wdst[c];
  int p = cnt_gt_rng(swss, -wd, 0, K_);
  float psp = sps[p];
  int r0 = rowptr2[c], m = ucnt[c];

  float mz = lrelu(swss[0] + wd);
  for (int s = 0; s < m; ++s) {
    float2 v = bval[r0 + s];
    mz = fmaxf(mz, lrelu(v.x + wd) + v.y);       // E > 0 (e_feat=1, LAMB=1)
  }

  float lo = mz - 1.0f, hi = mz;                 // g(mz)=0<1, g(mz-1)>=1
  int nmin = 0, nmax = K_;                       // support-count bracket
  for (int it = 0; it < 22; ++it) {
    float t = 0.5f * (lo + hi);
    float wthr = (t >= 0.f ? t : 5.f * t) - wd;
    int n = cnt_gt_rng(swss, wthr, nmin, nmax);
    float bsum = (n <= p) ? (sps[n] + n * wd)
                          : (psp + p * wd + NEG_ * (sps[n] - psp + (n - p) * wd));
    float g = bsum - n * t;
    for (int s = 0; s < m; ++s) {
      float2 v = bval[r0 + s];
      float bse = lrelu(v.x + wd);
      g += fmaxf(bse + v.y - t, 0.f) - fmaxf(bse - t, 0.f);
    }
    if (g > 1.f) { lo = t; nmax = n; } else { hi = t; nmin = n; }
  }
  float t = lo;                                  // t <= tau*, bracket ~2.4e-7
  float wthr = (t >= 0.f ? t : 5.f * t) - wd;
  int n = cnt_gt_rng(swss, wthr, nmin, nmax);
  float S = (n <= p) ? (sps[n] + n * wd)
                     : (psp + p * wd + NEG_ * (sps[n] - psp + (n - p) * wd));
  int cc = n;
  for (int s = 0; s < m; ++s) {
    float2 v = bval[r0 + s];
    float bse = lrelu(v.x + wd);
    float zz = bse + v.y;
    if (v.x > wthr) { S -= bse; cc -= 1; }       // same predicate as cnt -> exact cancel
    if (zz > t)     { S += zz;  cc += 1; }
  }
  float tau = (cc < 1) ? (mz - 1.0f) : ((S - 1.0f) / (float)cc);
  tau = fminf(fmaxf(tau, mz - 1.0f), mz);        // true tau* in [mz-1, mz)
  tauv[c] = tau;
}

// ---- dense weights: float4 per thread (820 = 205*4), coalesced dwordx4 ----
__global__ void k_dense(const float* __restrict__ wsrc, const float* __restrict__ wdst,
                        const float* __restrict__ tauv, float* __restrict__ out_w) {
  int t = threadIdx.x;
  int j4 = t * 4;
  if (j4 >= K_) return;
  int row = blockIdx.x;                         // b*K + i
  int b = row / K_;
  const float4* wd4 = (const float4*)(wdst + b * K_);
  const float4* ta4 = (const float4*)(tauv + b * K_);
  float ws = wsrc[row];
  float4 wd = wd4[t];
  float4 ta = ta4[t];
  float4 o;
  float z;
  z = lrelu(ws + wd.x) - ta.x; o.x = (z > 1e-9f) ? z : 0.f;
  z = lrelu(ws + wd.y) - ta.y; o.y = (z > 1e-9f) ? z : 0.f;
  z = lrelu(ws + wd.z) - ta.z; o.z = (z > 1e-9f) ? z : 0.f;
  z = lrelu(ws + wd.w) - ta.w; o.w = (z > 1e-9f) ? z : 0.f;
  ((float4*)(out_w + (size_t)row * K_))[t] = o;
}

// ---- rewrite the edge-perturbed entries with the correct value ----
__global__ void k_fix(const float* __restrict__ wsrc, const float* __restrict__ wdst,
                      const float* __restrict__ tauv, const int* __restrict__ rowptr2,
                      const int* __restrict__ ucnt, const int* __restrict__ colii,
                      const float* __restrict__ colval, float* __restrict__ out_w) {
  int c = blockIdx.x * 256 + threadIdx.x;
  int b = c / K_;
  int j = c - b * K_;
  float wd = wdst[c], ta = tauv[c];
  int r0 = rowptr2[c], m = ucnt[c];
  for (int s = 0; s < m; ++s) {
    int nr = colii[r0 + s];
    float z = lrelu(wsrc[nr] + wd) + colval[r0 + s];
    float v = z - ta;
    out_w[(size_t)nr * K_ + j] = (v > 1e-9f) ? v : 0.f;
  }
}

extern "C" void kernel_launch(void* const* d_in, const int* in_sizes, int n_in,
                              void* d_out, int out_size, void* d_ws, size_t ws_size,
                              hipStream_t stream) {
  const float* feat   = (const float*)d_in[0];
  const float* e_feat = (const float*)d_in[1];
  const float* W      = (const float*)d_in[2];
  const float* a      = (const float*)d_in[3];
  const float* att    = (const float*)d_in[4];
  const int*   src    = (const int*)d_in[5];
  const int*   dst    = (const int*)d_in[6];

  float* out_featp = (float*)d_out;                       // [BK*D]
  float* out_w     = out_featp + (size_t)BK_ * D_;        // [BK*K]
  float* out_perm  = out_w + (size_t)BK_ * K_;            // [BK]
  float* out_xs    = out_perm + BK_;                      // [NTOT]

  char* wsp = (char*)d_ws;
  auto carve = [&](size_t bytes) -> void* {
    void* pp = (void*)wsp;
    wsp += (bytes + 255) & ~(size_t)255;
    return pp;
  };
  float* waf       = (float*)carve((size_t)D_ * 4);
  float* wsrc      = (float*)carve((size_t)BK_ * 4);
  float* wdst      = (float*)carve((size_t)BK_ * 4);
  float* tauv      = (float*)carve((size_t)BK_ * 4);
  float* colval    = (float*)carve((size_t)ETOT_ * 4);
  float2* bval     = (float2*)carve((size_t)ETOT_ * 8);
  float* ws_sorted = (float*)carve((size_t)B_ * 1024 * 4);
  float* psum      = (float*)carve((size_t)B_ * 1025 * 4);
  int* rowptr      = (int*)carve((size_t)(NTOT_ + 1) * 4);
  int* rowptr2     = (int*)carve((size_t)(BK_ + 1) * 4);
  int* col         = (int*)carve((size_t)ETOT_ * 4);
  int* colii       = (int*)carve((size_t)ETOT_ * 4);
  int* perm_i      = (int*)carve((size_t)BK_ * 4);
  int* bsumA       = (int*)carve(64 * 4);
  int* bsumB       = (int*)carve(64 * 4);
  size_t zbytes    = ((size_t)NTOT_ * 3 + (size_t)BK_ * 2) * 4;
  int* zblk        = (int*)carve(zbytes);
  int* in_deg      = zblk;
  int* out_deg     = zblk + NTOT_;
  int* cursor      = zblk + 2 * NTOT_;
  int* cnt2        = zblk + 3 * NTOT_;
  int* cursor2     = cnt2 + BK_;
  int* maskarr     = (int*)carve((size_t)NTOT_ * 4);

  hipMemsetAsync(zblk, 0, zbytes, stream);
  hipMemsetAsync(maskarr, 0xFF, (size_t)NTOT_ * 4, stream);   // -1

  const int nbA = (NTOT_ + 1023) / 1024;   // 64
  const int nbB = (BK_ + 1023) / 1024;     // 52

  k_wa<<<1, 128, 0, stream>>>(W, a, waf);
  k_deg<<<ETOT_ / 256, 256, 0, stream>>>(src, dst, out_deg, in_deg);
  k_scansum<<<nbA, 256, 0, stream>>>(in_deg, NTOT_, bsumA);
  k_scanout<<<nbA, 256, 0, stream>>>(in_deg, NTOT_, bsumA, rowptr);
  k_fillcsr<<<ETOT_ / 256, 256, 0, stream>>>(dst, rowptr, cursor, col);
  k_agg<<<NTOT_ / 4, 256, 0, stream>>>(feat, e_feat, src, col, rowptr, out_deg, in_deg,
                                       waf, out_xs);
  k_topk<<<B_, 512, 0, stream>>>(out_xs, out_perm, perm_i, maskarr);
  k_gather<<<BK_ / 4, 256, 0, stream>>>(feat, perm_i, att, out_featp, wsrc, wdst);
  k_cnt2<<<ETOT_ / 256, 256, 0, stream>>>(src, dst, maskarr, cnt2);
  k_scansum<<<nbB, 256, 0, stream>>>(cnt2, BK_, bsumB);
  k_scanout<<<nbB, 256, 0, stream>>>(cnt2, BK_, bsumB, rowptr2);
  k_fill2<<<ETOT_ / 256, 256, 0, stream>>>(src, dst, maskarr, e_feat, rowptr2, cursor2,
                                           colii, colval);
  k_dedupe<<<BK_ / 256, 256, 0, stream>>>(rowptr2, colii, colval, cursor2, wsrc, bval);
  k_gsort<<<B_, 512, 0, stream>>>(wsrc, ws_sorted, psum);
  k_tau<<<B_ * CPB_, 128, 0, stream>>>(wdst, ws_sorted, psum, rowptr2, cursor2,
                                       bval, tauv);
  k_dense<<<BK_, 256, 0, stream>>>(wsrc, wdst, tauv, out_w);
  k_fix<<<BK_ / 256, 256, 0, stream>>>(wsrc, wdst, tauv, rowptr2, cursor2, colii, colval,
                                       out_w);
}